// Round 1
// baseline (680.338 us; speedup 1.0000x reference)
//
#include <hip/hip_runtime.h>
#include <math.h>

// ---------------------------------------------------------------------------
// out = (silu(x) @ (W/sigma)^T + b  +  softthr(basis(x) @ Ww^T)) * oscale
// sigma from one power iteration: sigma = ||W t||^2-ish with t = W^T u.
// Strategy: bf16 MFMA GEMMs (fp32 accum), activations materialized in ws.
// ---------------------------------------------------------------------------

typedef __attribute__((ext_vector_type(4))) float  f32x4;
typedef __attribute__((ext_vector_type(8))) __bf16 bf16x8;
typedef __attribute__((ext_vector_type(4))) unsigned short u16x4;
typedef __attribute__((ext_vector_type(8))) unsigned short u16x8;

#define NROWS 16384
#define INF   1024
#define OUTF  1024
#define GG    7
#define KKAN  7168   // INF*GG

static __device__ __forceinline__ unsigned short f2bf(float f) {
  union { float f; unsigned int u; } v; v.f = f;
  unsigned int r = v.u + 0x7fffu + ((v.u >> 16) & 1u);  // RNE
  return (unsigned short)(r >> 16);
}

// ---------------- sigma (spectral norm) ----------------
__global__ void mv_wt_u(const float* __restrict__ W, const float* __restrict__ u,
                        float* __restrict__ t) {
  int j = blockIdx.x;               // 1024 blocks, one column each
  int tid = threadIdx.x;
  float p = 0.f;
  for (int i = tid; i < OUTF; i += 256) p += W[(size_t)i * INF + j] * u[i];
  __shared__ float red[256];
  red[tid] = p; __syncthreads();
  for (int s = 128; s > 0; s >>= 1) { if (tid < s) red[tid] += red[tid + s]; __syncthreads(); }
  if (tid == 0) t[j] = red[0];
}

__global__ void mv_w_t(const float* __restrict__ W, const float* __restrict__ t,
                       float* __restrict__ s) {
  int i = blockIdx.x;               // one row each, coalesced
  int tid = threadIdx.x;
  float p = 0.f;
  for (int j = tid; j < INF; j += 256) p += W[(size_t)i * INF + j] * t[j];
  __shared__ float red[256];
  red[tid] = p; __syncthreads();
  for (int k = 128; k > 0; k >>= 1) { if (tid < k) red[tid] += red[tid + k]; __syncthreads(); }
  if (tid == 0) s[i] = red[0];
}

__global__ void sigma_finish(const float* __restrict__ t, const float* __restrict__ s,
                             const float* __restrict__ st, const float* __restrict__ os,
                             float* __restrict__ scal) {
  __shared__ float r1[256], r2[256];
  int tid = threadIdx.x;
  float p1 = 0.f, p2 = 0.f;
  for (int i = tid; i < 1024; i += 256) { float a = t[i]; p1 += a * a; float b = s[i]; p2 += b * b; }
  r1[tid] = p1; r2[tid] = p2; __syncthreads();
  for (int k = 128; k > 0; k >>= 1) { if (tid < k) { r1[tid] += r1[tid + k]; r2[tid] += r2[tid + k]; } __syncthreads(); }
  if (tid == 0) {
    float nt = sqrtf(r1[0]);
    float ns = sqrtf(r2[0]);
    float nq = ns / (nt + 1e-12f);               // ||W v||
    float sigma = nq * nq / (nq + 1e-12f);       // u2 . (W v)
    scal[0] = 1.f / sigma;
    scal[1] = log1pf(__expf(st[0]));             // softplus(soft_threshold)
    scal[2] = os[0];                             // output_scale
  }
}

// ---------------- weight casts ----------------
__global__ void wsn_cast(const float* __restrict__ w, const float* __restrict__ scal,
                         unsigned short* __restrict__ o) {
  float is = scal[0];
  int idx = blockIdx.x * 256 + threadIdx.x;      // 131072 threads, 8 elems each
  const f32x4* p = (const f32x4*)(w + (size_t)idx * 8);
  f32x4 a = p[0], b = p[1];
  u16x8 v;
  v[0] = f2bf(a[0] * is); v[1] = f2bf(a[1] * is); v[2] = f2bf(a[2] * is); v[3] = f2bf(a[3] * is);
  v[4] = f2bf(b[0] * is); v[5] = f2bf(b[1] * is); v[6] = f2bf(b[2] * is); v[7] = f2bf(b[3] * is);
  *(u16x8*)(o + (size_t)idx * 8) = v;
}

// wavelet_w [o][i*7+g]  ->  bf16 [o][g*1024+i]   (g-major K layout)
__global__ void wkan_cast(const float* __restrict__ w, unsigned short* __restrict__ o) {
  int orow = blockIdx.x;                          // 1024 blocks
  const float* src0 = w + (size_t)orow * KKAN;
  unsigned short* dst0 = o + (size_t)orow * KKAN;
  for (int r = threadIdx.x; r < 896; r += 256) {  // 896 = 7*128 vec8-units per row
    int g = r >> 7, i0 = (r & 127) << 3;
    u16x8 v;
#pragma unroll
    for (int j = 0; j < 8; j++) v[j] = f2bf(src0[(size_t)(i0 + j) * GG + g]);
    *(u16x8*)(dst0 + g * 1024 + i0) = v;
  }
}

// ---------------- activation expansion ----------------
__global__ void expand_kernel(const float* __restrict__ x,
                              const float* __restrict__ translation,
                              const float* __restrict__ scale,
                              unsigned short* __restrict__ a_base,   // [nrows][1024]
                              unsigned short* __restrict__ a_kan,    // [nrows][7168] g-major
                              int row0, int nrows) {
  float tr[GG], iss[GG];
#pragma unroll
  for (int g = 0; g < GG; g++) {
    tr[g] = translation[g];
    float s = fabsf(scale[g]);
    iss[g] = 1.f / (s < 0.1f ? 0.1f : s);
  }
  int units = nrows * (INF / 8);
  int stride = gridDim.x * blockDim.x;
  for (int uu = blockIdx.x * blockDim.x + threadIdx.x; uu < units; uu += stride) {
    int nloc = uu >> 7;
    int i0 = (uu & 127) << 3;
    const f32x4* xp = (const f32x4*)(x + (size_t)(row0 + nloc) * INF + i0);
    f32x4 xa = xp[0], xb = xp[1];
    float xv[8] = {xa[0], xa[1], xa[2], xa[3], xb[0], xb[1], xb[2], xb[3]};
    u16x8 sb, kb[GG];
#pragma unroll
    for (int j = 0; j < 8; j++) {
      float xx = xv[j];
      float si = xx / (1.f + __expf(-xx));        // silu
      sb[j] = f2bf(si);
      float e2 = __expf(2.f * xx);                // tanh via exp
      float xn = 2.5f * (1.f - 2.f / (e2 + 1.f));
#pragma unroll
      for (int g = 0; g < GG; g++) {
        float xe = (xn - tr[g]) * iss[g];
        float t2 = xe * xe;
        float b = (1.f - t2) * __expf(-0.5f * t2);
        kb[g][j] = f2bf(b);
      }
    }
    *(u16x8*)(a_base + (size_t)nloc * INF + i0) = sb;
    unsigned short* kp = a_kan + (size_t)nloc * KKAN + i0;
#pragma unroll
    for (int g = 0; g < GG; g++) *(u16x8*)(kp + g * 1024) = kb[g];
  }
}

// ---------------- GEMM: C[128x128] tiles, 4 waves, 16x16x32 bf16 MFMA ------
// LDS tiles [128 rows][64 k] bf16, XOR-swizzled 16B chunks: chunk p of row r
// holds k-chunk p^(r&7).  Staged via global_load_lds(16B) with pre-swizzled
// per-lane global source (both-sides swizzle); frag reads are ds_read_b128.

static __device__ __forceinline__ void gload16(const unsigned short* g, unsigned short* l) {
  __builtin_amdgcn_global_load_lds(
      (const __attribute__((address_space(1))) unsigned int*)g,
      (__attribute__((address_space(3))) unsigned int*)l, 16, 0, 0);
}

static __device__ __forceinline__ bf16x8 ldfrag(const unsigned short* base, int row, int kbyte) {
  const char* bp = (const char*)base + row * 128 + (kbyte ^ ((row & 7) << 4));
  return *(const bf16x8*)bp;
}

template <int MODE>   // 0: out = acc + bias   1: out = (out + softthr(acc)) * oscale
__global__ __launch_bounds__(256) void gemm_kernel(
    const unsigned short* __restrict__ A,   // [mtiles*128][K] bf16
    const unsigned short* __restrict__ W,   // [1024][K] bf16
    const float* __restrict__ bias,
    const float* __restrict__ scal,
    float* __restrict__ out,                // [mtiles*128][1024]
    int K, int mtiles) {
  __shared__ unsigned short As[128 * 64];
  __shared__ unsigned short Bs[128 * 64];

  int bid = blockIdx.x;
  int n = bid & 7;            // 8 N-tiles; m-major order => A-panel L2/L3 reuse
  int m = bid >> 3;
  int tid = threadIdx.x;
  int w = tid >> 6, l = tid & 63;
  int wr = w >> 1, wc = w & 1;

  int swk = ((l & 7) ^ (l >> 3)) * 8;       // pre-swizzled k-chunk for staging
  const unsigned short* Ab = A + (size_t)(m * 128 + w * 32 + (l >> 3)) * K + swk;
  const unsigned short* Wb = W + (size_t)(n * 128 + w * 32 + (l >> 3)) * K + swk;
  unsigned short* Al = As + (w * 32) * 64;
  unsigned short* Bl = Bs + (w * 32) * 64;

  f32x4 acc[4][4] = {};

  for (int k0 = 0; k0 < K; k0 += 64) {
#pragma unroll
    for (int p = 0; p < 4; p++) {
      gload16(Ab + (size_t)(p * 8) * K + k0, Al + p * 8 * 64);
      gload16(Wb + (size_t)(p * 8) * K + k0, Bl + p * 8 * 64);
    }
    __syncthreads();
#pragma unroll
    for (int ks = 0; ks < 64; ks += 32) {
      int kbyte = ks * 2 + ((l >> 4) << 4);
      bf16x8 af[4], bfr[4];
#pragma unroll
      for (int i = 0; i < 4; i++) af[i] = ldfrag(As, wr * 64 + i * 16 + (l & 15), kbyte);
#pragma unroll
      for (int i = 0; i < 4; i++) bfr[i] = ldfrag(Bs, wc * 64 + i * 16 + (l & 15), kbyte);
#pragma unroll
      for (int i = 0; i < 4; i++)
#pragma unroll
        for (int j = 0; j < 4; j++)
          acc[i][j] = __builtin_amdgcn_mfma_f32_16x16x32_bf16(af[i], bfr[j], acc[i][j], 0, 0, 0);
    }
    __syncthreads();
  }

  float thr = scal[1], osc = scal[2];
  int r0 = m * 128 + wr * 64 + ((l >> 4) << 2);
  int c0 = n * 128 + wc * 64 + (l & 15);
#pragma unroll
  for (int i = 0; i < 4; i++)
#pragma unroll
    for (int j = 0; j < 4; j++) {
      int c = c0 + j * 16;
#pragma unroll
      for (int q = 0; q < 4; q++) {
        int r = r0 + i * 16 + q;
        size_t idx = (size_t)r * OUTF + c;
        float v = acc[i][j][q];
        if (MODE == 0) {
          out[idx] = v + bias[c];
        } else {
          float a = fabsf(v) - thr;
          float kan = a > 0.f ? (v > 0.f ? a : -a) : 0.f;
          out[idx] = (out[idx] + kan) * osc;
        }
      }
    }
}

// ---------------------------------------------------------------------------
extern "C" void kernel_launch(void* const* d_in, const int* in_sizes, int n_in,
                              void* d_out, int out_size, void* d_ws, size_t ws_size,
                              hipStream_t stream) {
  const float* x              = (const float*)d_in[0];
  const float* base_w         = (const float*)d_in[1];
  const float* base_b         = (const float*)d_in[2];
  const float* u              = (const float*)d_in[3];
  const float* translation    = (const float*)d_in[4];
  const float* scale          = (const float*)d_in[5];
  const float* wavelet_w      = (const float*)d_in[6];
  const float* soft_threshold = (const float*)d_in[7];
  const float* output_scale   = (const float*)d_in[8];
  float* out = (float*)d_out;

  char* ws = (char*)d_ws;
  float* t_vec = (float*)ws;                    // 1024 f32
  float* s_vec = t_vec + 1024;                  // 1024 f32
  float* scal  = s_vec + 1024;                  // [inv_sigma, thr, oscale]
  unsigned short* wsn  = (unsigned short*)(ws + 16384);
  unsigned short* wkan = (unsigned short*)(ws + 16384 + (size_t)2 * 1024 * 1024);
  char* chunkbuf = ws + 16384 + (size_t)2 * 1024 * 1024 + (size_t)14 * 1024 * 1024;

  size_t fixed = 16384 + (size_t)2 * 1024 * 1024 + (size_t)14 * 1024 * 1024;
  size_t avail = ws_size > fixed ? ws_size - fixed : 0;
  long mc = (long)(avail / ((INF + KKAN) * 2));  // rows of A panels that fit
  if (mc > NROWS) mc = NROWS;
  mc -= mc % 128;
  if (mc < 128) mc = 128;                        // assume ws >= ~19MB

  // sigma + scalars
  mv_wt_u<<<1024, 256, 0, stream>>>(base_w, u, t_vec);
  mv_w_t<<<1024, 256, 0, stream>>>(base_w, t_vec, s_vec);
  sigma_finish<<<1, 256, 0, stream>>>(t_vec, s_vec, soft_threshold, output_scale, scal);

  // weight casts
  wsn_cast<<<512, 256, 0, stream>>>(base_w, scal, wsn);
  wkan_cast<<<1024, 256, 0, stream>>>(wavelet_w, wkan);

  unsigned short* a_base = (unsigned short*)chunkbuf;
  unsigned short* a_kan  = a_base + (size_t)mc * INF;

  for (long r0 = 0; r0 < NROWS; r0 += mc) {
    long nr = (NROWS - r0 < mc) ? (NROWS - r0) : mc;
    expand_kernel<<<2048, 256, 0, stream>>>(x, translation, scale, a_base, a_kan,
                                            (int)r0, (int)nr);
    int mt = (int)(nr / 128);
    gemm_kernel<0><<<mt * 8, 256, 0, stream>>>(a_base, wsn, base_b, scal,
                                               out + (size_t)r0 * OUTF, INF, mt);
    gemm_kernel<1><<<mt * 8, 256, 0, stream>>>(a_kan, wkan, base_b, scal,
                                               out + (size_t)r0 * OUTF, KKAN, mt);
  }
}

// Round 2
// 518.016 us; speedup vs baseline: 1.3134x; 1.3134x over previous
//
#include <hip/hip_runtime.h>
#include <math.h>

// ---------------------------------------------------------------------------
// out = (silu(x) @ (W/sigma)^T + b  +  softthr(basis(x) @ Ww^T)) * oscale
// bf16 MFMA GEMMs with the 256x256 8-phase counted-vmcnt schedule (m201).
// ---------------------------------------------------------------------------

typedef __attribute__((ext_vector_type(4))) float  f32x4;
typedef __attribute__((ext_vector_type(8))) __bf16 bf16x8;
typedef __attribute__((ext_vector_type(8))) unsigned short u16x8;

#define NROWS 16384
#define INF   1024
#define OUTF  1024
#define GG    7
#define KKAN  7168   // INF*GG

static __device__ __forceinline__ unsigned short f2bf(float f) {
  union { float f; unsigned int u; } v; v.f = f;
  unsigned int r = v.u + 0x7fffu + ((v.u >> 16) & 1u);  // RNE
  return (unsigned short)(r >> 16);
}

// ---------------- sigma (spectral norm) ----------------
__global__ void mv_wt_u(const float* __restrict__ W, const float* __restrict__ u,
                        float* __restrict__ t) {
  int j = blockIdx.x;
  int tid = threadIdx.x;
  float p = 0.f;
  for (int i = tid; i < OUTF; i += 256) p += W[(size_t)i * INF + j] * u[i];
  __shared__ float red[256];
  red[tid] = p; __syncthreads();
  for (int s = 128; s > 0; s >>= 1) { if (tid < s) red[tid] += red[tid + s]; __syncthreads(); }
  if (tid == 0) t[j] = red[0];
}

__global__ void mv_w_t(const float* __restrict__ W, const float* __restrict__ t,
                       float* __restrict__ s) {
  int i = blockIdx.x;
  int tid = threadIdx.x;
  float p = 0.f;
  for (int j = tid; j < INF; j += 256) p += W[(size_t)i * INF + j] * t[j];
  __shared__ float red[256];
  red[tid] = p; __syncthreads();
  for (int k = 128; k > 0; k >>= 1) { if (tid < k) red[tid] += red[tid + k]; __syncthreads(); }
  if (tid == 0) s[i] = red[0];
}

__global__ void sigma_finish(const float* __restrict__ t, const float* __restrict__ s,
                             const float* __restrict__ st, const float* __restrict__ os,
                             float* __restrict__ scal) {
  __shared__ float r1[256], r2[256];
  int tid = threadIdx.x;
  float p1 = 0.f, p2 = 0.f;
  for (int i = tid; i < 1024; i += 256) { float a = t[i]; p1 += a * a; float b = s[i]; p2 += b * b; }
  r1[tid] = p1; r2[tid] = p2; __syncthreads();
  for (int k = 128; k > 0; k >>= 1) { if (tid < k) { r1[tid] += r1[tid + k]; r2[tid] += r2[tid + k]; } __syncthreads(); }
  if (tid == 0) {
    float nt = sqrtf(r1[0]);
    float ns = sqrtf(r2[0]);
    float nq = ns / (nt + 1e-12f);
    float sigma = nq * nq / (nq + 1e-12f);
    scal[0] = 1.f / sigma;
    scal[1] = log1pf(__expf(st[0]));
    scal[2] = os[0];
  }
}

// ---------------- weight casts ----------------
__global__ void wsn_cast(const float* __restrict__ w, const float* __restrict__ scal,
                         unsigned short* __restrict__ o) {
  float is = scal[0];
  int idx = blockIdx.x * 256 + threadIdx.x;
  const f32x4* p = (const f32x4*)(w + (size_t)idx * 8);
  f32x4 a = p[0], b = p[1];
  u16x8 v;
  v[0] = f2bf(a[0] * is); v[1] = f2bf(a[1] * is); v[2] = f2bf(a[2] * is); v[3] = f2bf(a[3] * is);
  v[4] = f2bf(b[0] * is); v[5] = f2bf(b[1] * is); v[6] = f2bf(b[2] * is); v[7] = f2bf(b[3] * is);
  *(u16x8*)(o + (size_t)idx * 8) = v;
}

__global__ void wkan_cast(const float* __restrict__ w, unsigned short* __restrict__ o) {
  int orow = blockIdx.x;
  const float* src0 = w + (size_t)orow * KKAN;
  unsigned short* dst0 = o + (size_t)orow * KKAN;
  for (int r = threadIdx.x; r < 896; r += 256) {
    int g = r >> 7, i0 = (r & 127) << 3;
    u16x8 v;
#pragma unroll
    for (int j = 0; j < 8; j++) v[j] = f2bf(src0[(size_t)(i0 + j) * GG + g]);
    *(u16x8*)(dst0 + g * 1024 + i0) = v;
  }
}

// ---------------- activation expansion ----------------
__global__ void expand_kernel(const float* __restrict__ x,
                              const float* __restrict__ translation,
                              const float* __restrict__ scale,
                              unsigned short* __restrict__ a_base,
                              unsigned short* __restrict__ a_kan,
                              int row0, int nrows) {
  float tr[GG], iss[GG];
#pragma unroll
  for (int g = 0; g < GG; g++) {
    tr[g] = translation[g];
    float s = fabsf(scale[g]);
    iss[g] = 1.f / (s < 0.1f ? 0.1f : s);
  }
  int units = nrows * (INF / 8);
  int stride = gridDim.x * blockDim.x;
  for (int uu = blockIdx.x * blockDim.x + threadIdx.x; uu < units; uu += stride) {
    int nloc = uu >> 7;
    int i0 = (uu & 127) << 3;
    const f32x4* xp = (const f32x4*)(x + (size_t)(row0 + nloc) * INF + i0);
    f32x4 xa = xp[0], xb = xp[1];
    float xv[8] = {xa[0], xa[1], xa[2], xa[3], xb[0], xb[1], xb[2], xb[3]};
    u16x8 sb, kb[GG];
#pragma unroll
    for (int j = 0; j < 8; j++) {
      float xx = xv[j];
      float si = xx / (1.f + __expf(-xx));
      sb[j] = f2bf(si);
      float e2 = __expf(2.f * xx);
      float xn = 2.5f * (1.f - 2.f / (e2 + 1.f));
#pragma unroll
      for (int g = 0; g < GG; g++) {
        float xe = (xn - tr[g]) * iss[g];
        float t2 = xe * xe;
        float b = (1.f - t2) * __expf(-0.5f * t2);
        kb[g][j] = f2bf(b);
      }
    }
    *(u16x8*)(a_base + (size_t)nloc * INF + i0) = sb;
    unsigned short* kp = a_kan + (size_t)nloc * KKAN + i0;
#pragma unroll
    for (int g = 0; g < GG; g++) *(u16x8*)(kp + g * 1024) = kb[g];
  }
}

// ---------------- 256x256 8-phase GEMM ----------------
static __device__ __forceinline__ void gload16(const unsigned short* g, unsigned short* l) {
  __builtin_amdgcn_global_load_lds(
      (const __attribute__((address_space(1))) unsigned int*)g,
      (__attribute__((address_space(3))) unsigned int*)l, 16, 0, 0);
}

#define SBAR  do { __builtin_amdgcn_sched_barrier(0); __builtin_amdgcn_s_barrier(); } while (0)
#define LGKM0 do { asm volatile("s_waitcnt lgkmcnt(0)" ::: "memory"); __builtin_amdgcn_sched_barrier(0); } while (0)
#define VM(N) asm volatile("s_waitcnt vmcnt(" #N ")" ::: "memory")

// stage one half-tile (128 rows x 64 k) of matrix X: 2 global_load_lds per thread
#define STAGE(gp, ld, bb, hh, tt) do { \
    const unsigned short* _s = (gp) + (size_t)((hh) * 128) * K + (size_t)(tt) * 64; \
    unsigned short* _d = (ld) + (bb) * 16384 + (hh) * 8192; \
    gload16(_s, _d); \
    gload16(_s + (size_t)64 * K, _d + 4096); \
  } while (0)

#define RDA(qq, bb) do { _Pragma("unroll") for (int i = 0; i < 4; ++i) { \
    const char* _p = pA + (bb) * 32768 + (qq) * 16384 + i * 2048; \
    af[i][0] = *(const bf16x8*)(_p + kx0); \
    af[i][1] = *(const bf16x8*)(_p + kx1); } } while (0)

#define RDB(dst, hh, bb) do { _Pragma("unroll") for (int j = 0; j < 2; ++j) { \
    const char* _p = pB + (bb) * 32768 + (hh) * 16384 + j * 2048; \
    dst[j][0] = *(const bf16x8*)(_p + kx0); \
    dst[j][1] = *(const bf16x8*)(_p + kx1); } } while (0)

#define MM(qq, pp, B) do { _Pragma("unroll") for (int i = 0; i < 4; ++i) \
    _Pragma("unroll") for (int j = 0; j < 2; ++j) \
    _Pragma("unroll") for (int k = 0; k < 2; ++k) \
      acc[qq][i][pp][j] = __builtin_amdgcn_mfma_f32_16x16x32_bf16(af[i][k], B[j][k], acc[qq][i][pp][j], 0, 0, 0); } while (0)

// one K-tile: 4 phases; issue stream = [B1(t+1), A0(t+2), B0(t+2), A1(t+2)]
#define TILE(tt, bb, S1, S2, S3, S4, WAIT) do { \
    /* phase 1: reads A0(12 with B0), MFMA quadrant (0,0) */ \
    RDA(0, bb); RDB(bf0, 0, bb); \
    if (S1) STAGE(gB, ldB, (bb) ^ 1, 1, (tt) + 1); \
    asm volatile("s_waitcnt lgkmcnt(8)" ::: "memory"); \
    SBAR; LGKM0; \
    __builtin_amdgcn_s_setprio(1); MM(0, 0, bf0); __builtin_amdgcn_s_setprio(0); \
    SBAR; \
    /* phase 2: reads B1, MFMA (0,1) */ \
    RDB(bf1, 1, bb); \
    if (S2) STAGE(gA, ldA, bb, 0, (tt) + 2); \
    SBAR; LGKM0; \
    __builtin_amdgcn_s_setprio(1); MM(0, 1, bf1); __builtin_amdgcn_s_setprio(0); \
    SBAR; \
    /* phase 3: reads A1, MFMA (1,0) */ \
    RDA(1, bb); \
    if (S3) STAGE(gB, ldB, bb, 0, (tt) + 2); \
    SBAR; LGKM0; \
    __builtin_amdgcn_s_setprio(1); MM(1, 0, bf0); __builtin_amdgcn_s_setprio(0); \
    SBAR; \
    /* phase 4: no reads, MFMA (1,1), counted vmcnt */ \
    if (S4) STAGE(gA, ldA, bb, 1, (tt) + 2); \
    SBAR; \
    __builtin_amdgcn_s_setprio(1); MM(1, 1, bf1); __builtin_amdgcn_s_setprio(0); \
    WAIT; \
    SBAR; \
  } while (0)

template <int MODE, int K>   // 0: out = acc + bias   1: out = (out + softthr(acc)) * oscale
__global__ __launch_bounds__(512, 2) void gemm8(
    const unsigned short* __restrict__ A,   // [mtiles*256][K] bf16
    const unsigned short* __restrict__ W,   // [1024][K] bf16
    const float* __restrict__ bias,
    const float* __restrict__ scal,
    float* __restrict__ out) {              // [mtiles*256][1024]
  __shared__ unsigned short lds[65536];     // A: [0,32768) shorts, B: [32768,65536)
  constexpr int NT = K / 64;

  int bid = blockIdx.x;
  int cpx = gridDim.x >> 3;                 // bijective XCD swizzle (nwg % 8 == 0)
  int swz = (bid & 7) * cpx + (bid >> 3);
  int m0 = (swz >> 2) * 256;
  int n0 = (swz & 3) * 256;
  int tid = threadIdx.x;
  int wv = tid >> 6, l = tid & 63;
  int wr = wv >> 2, wc = wv & 3;

  // staging: thread covers row (tid>>3), swizzled 16B k-chunk (both-sides XOR)
  int rowq = tid >> 3;
  int swk = ((tid & 7) ^ (rowq & 7)) << 3;
  const unsigned short* gA = A + (size_t)(m0 + rowq) * K + swk;
  const unsigned short* gB = W + (size_t)(n0 + rowq) * K + swk;
  unsigned short* ldA = lds + wv * 512;
  unsigned short* ldB = lds + 32768 + wv * 512;

  // frag reads
  int lr = l & 15;
  int kb = (l >> 4) << 4;                   // 0/16/32/48 bytes within K=32 step
  int xr = (l & 7) << 4;                    // row&7 == l&7 for all frag rows
  int kx0 = kb ^ xr;
  int kx1 = (64 | kb) ^ xr;
  const char* pA = (const char*)lds + (wr * 64 + lr) * 128;
  const char* pB = (const char*)lds + 65536 + (wc * 32 + lr) * 128;

  bf16x8 af[4][2], bf0[2][2], bf1[2][2];
  f32x4 acc[2][4][2][2] = {};

  // prologue: tiles 0 fully + {A0,B0,A1}(1) in flight; wait oldest -> vmcnt(6)
  STAGE(gA, ldA, 0, 0, 0);
  STAGE(gB, ldB, 0, 0, 0);
  STAGE(gA, ldA, 0, 1, 0);
  STAGE(gB, ldB, 0, 1, 0);
  STAGE(gA, ldA, 1, 0, 1);
  STAGE(gB, ldB, 1, 0, 1);
  STAGE(gA, ldA, 1, 1, 1);
  VM(6);
  SBAR;

  for (int t = 0; t < NT - 2; t += 2) {
    TILE(t,     0, 1, 1, 1, 1, VM(6));
    TILE(t + 1, 1, 1, 1, 1, 1, VM(6));
  }
  TILE(NT - 2, 0, 1, 0, 0, 0, VM(0));   // stage only B1(NT-1); drain
  TILE(NT - 1, 1, 0, 0, 0, 0, (void)0);

  // epilogue
  float thr = scal[1], osc = scal[2];
  int rr = m0 + wr * 64 + ((l >> 4) << 2);
  int cc = n0 + wc * 32 + lr;
#pragma unroll
  for (int q = 0; q < 2; ++q)
#pragma unroll
    for (int i = 0; i < 4; ++i)
#pragma unroll
      for (int p = 0; p < 2; ++p)
#pragma unroll
        for (int j = 0; j < 2; ++j) {
          int c = cc + p * 128 + j * 16;
#pragma unroll
          for (int e = 0; e < 4; ++e) {
            int r = rr + q * 128 + i * 16 + e;
            size_t idx = (size_t)r * OUTF + c;
            float v = acc[q][i][p][j][e];
            if (MODE == 0) {
              out[idx] = v + bias[c];
            } else {
              float a = fabsf(v) - thr;
              float kan = a > 0.f ? (v > 0.f ? a : -a) : 0.f;
              out[idx] = (out[idx] + kan) * osc;
            }
          }
        }
}

// ---------------------------------------------------------------------------
extern "C" void kernel_launch(void* const* d_in, const int* in_sizes, int n_in,
                              void* d_out, int out_size, void* d_ws, size_t ws_size,
                              hipStream_t stream) {
  const float* x              = (const float*)d_in[0];
  const float* base_w         = (const float*)d_in[1];
  const float* base_b         = (const float*)d_in[2];
  const float* u              = (const float*)d_in[3];
  const float* translation    = (const float*)d_in[4];
  const float* scale          = (const float*)d_in[5];
  const float* wavelet_w      = (const float*)d_in[6];
  const float* soft_threshold = (const float*)d_in[7];
  const float* output_scale   = (const float*)d_in[8];
  float* out = (float*)d_out;

  char* ws = (char*)d_ws;
  float* t_vec = (float*)ws;
  float* s_vec = t_vec + 1024;
  float* scal  = s_vec + 1024;
  unsigned short* wsn  = (unsigned short*)(ws + 16384);
  unsigned short* wkan = (unsigned short*)(ws + 16384 + (size_t)2 * 1024 * 1024);
  char* chunkbuf = ws + 16384 + (size_t)2 * 1024 * 1024 + (size_t)14 * 1024 * 1024;

  size_t fixed = 16384 + (size_t)2 * 1024 * 1024 + (size_t)14 * 1024 * 1024;
  size_t avail = ws_size > fixed ? ws_size - fixed : 0;
  long mc = (long)(avail / ((INF + KKAN) * 2));
  if (mc > NROWS) mc = NROWS;
  mc -= mc % 512;
  if (mc < 512) mc = 512;

  mv_wt_u<<<1024, 256, 0, stream>>>(base_w, u, t_vec);
  mv_w_t<<<1024, 256, 0, stream>>>(base_w, t_vec, s_vec);
  sigma_finish<<<1, 256, 0, stream>>>(t_vec, s_vec, soft_threshold, output_scale, scal);

  wsn_cast<<<512, 256, 0, stream>>>(base_w, scal, wsn);
  wkan_cast<<<1024, 256, 0, stream>>>(wavelet_w, wkan);

  unsigned short* a_base = (unsigned short*)chunkbuf;
  unsigned short* a_kan  = a_base + (size_t)mc * INF;

  for (long r0 = 0; r0 < NROWS; r0 += mc) {
    long nr = (NROWS - r0 < mc) ? (NROWS - r0) : mc;
    expand_kernel<<<2048, 256, 0, stream>>>(x, translation, scale, a_base, a_kan,
                                            (int)r0, (int)nr);
    int mt = (int)(nr / 256);
    gemm8<0, 1024><<<mt * 4, 512, 0, stream>>>(a_base, wsn, base_b, scal,
                                               out + (size_t)r0 * OUTF);
    gemm8<1, KKAN><<<mt * 4, 512, 0, stream>>>(a_kan, wkan, base_b, scal,
                                               out + (size_t)r0 * OUTF);
  }
}

// Round 3
// 476.843 us; speedup vs baseline: 1.4268x; 1.0863x over previous
//
#include <hip/hip_runtime.h>
#include <math.h>

// ---------------------------------------------------------------------------
// out = (silu(x) @ (W/sigma)^T + b  +  softthr(basis(x) @ Ww^T)) * oscale
// Single merged bf16 MFMA GEMM, K = [kan 7168 | base 1024] = 8192, with the
// 256x256 8-phase counted-vmcnt schedule; softthr applied in-register at the
// K-tile boundary so base accumulates on top (no out RMW, one epilogue).
// ---------------------------------------------------------------------------

typedef __attribute__((ext_vector_type(4))) float  f32x4;
typedef __attribute__((ext_vector_type(8))) __bf16 bf16x8;
typedef __attribute__((ext_vector_type(8))) unsigned short u16x8;

#define NROWS 16384
#define INF   1024
#define OUTF  1024
#define GG    7
#define KKAN  7168   // INF*GG
#define KTOT  8192   // KKAN + INF

static __device__ __forceinline__ unsigned short f2bf(float f) {
  union { float f; unsigned int u; } v; v.f = f;
  unsigned int r = v.u + 0x7fffu + ((v.u >> 16) & 1u);  // RNE
  return (unsigned short)(r >> 16);
}

// ---------------- sigma (spectral norm) ----------------
__global__ void mv_wt_u(const float* __restrict__ W, const float* __restrict__ u,
                        float* __restrict__ t) {
  int j = blockIdx.x;
  int tid = threadIdx.x;
  float p = 0.f;
  for (int i = tid; i < OUTF; i += 256) p += W[(size_t)i * INF + j] * u[i];
  __shared__ float red[256];
  red[tid] = p; __syncthreads();
  for (int s = 128; s > 0; s >>= 1) { if (tid < s) red[tid] += red[tid + s]; __syncthreads(); }
  if (tid == 0) t[j] = red[0];
}

__global__ void mv_w_t(const float* __restrict__ W, const float* __restrict__ t,
                       float* __restrict__ s) {
  int i = blockIdx.x;
  int tid = threadIdx.x;
  float p = 0.f;
  for (int j = tid; j < INF; j += 256) p += W[(size_t)i * INF + j] * t[j];
  __shared__ float red[256];
  red[tid] = p; __syncthreads();
  for (int k = 128; k > 0; k >>= 1) { if (tid < k) red[tid] += red[tid + k]; __syncthreads(); }
  if (tid == 0) s[i] = red[0];
}

__global__ void sigma_finish(const float* __restrict__ t, const float* __restrict__ s,
                             const float* __restrict__ st, const float* __restrict__ os,
                             float* __restrict__ scal) {
  __shared__ float r1[256], r2[256];
  int tid = threadIdx.x;
  float p1 = 0.f, p2 = 0.f;
  for (int i = tid; i < 1024; i += 256) { float a = t[i]; p1 += a * a; float b = s[i]; p2 += b * b; }
  r1[tid] = p1; r2[tid] = p2; __syncthreads();
  for (int k = 128; k > 0; k >>= 1) { if (tid < k) { r1[tid] += r1[tid + k]; r2[tid] += r2[tid + k]; } __syncthreads(); }
  if (tid == 0) {
    float nt = sqrtf(r1[0]);
    float ns = sqrtf(r2[0]);
    float nq = ns / (nt + 1e-12f);
    float sigma = nq * nq / (nq + 1e-12f);
    scal[0] = 1.f / sigma;
    scal[1] = log1pf(__expf(st[0]));
    scal[2] = os[0];
  }
}

// ---------------- weight casts into merged W' [1024][8192] ----------------
// cols [0,7168) = wavelet (g-major), cols [7168,8192) = W/sigma
__global__ void wsn_cast(const float* __restrict__ w, const float* __restrict__ scal,
                         unsigned short* __restrict__ Wp) {
  float is = scal[0];
  int idx = blockIdx.x * 256 + threadIdx.x;      // 131072 vec8 units
  int row = idx >> 7, i0 = (idx & 127) << 3;
  const f32x4* p = (const f32x4*)(w + (size_t)row * INF + i0);
  f32x4 a = p[0], b = p[1];
  u16x8 v;
  v[0] = f2bf(a[0] * is); v[1] = f2bf(a[1] * is); v[2] = f2bf(a[2] * is); v[3] = f2bf(a[3] * is);
  v[4] = f2bf(b[0] * is); v[5] = f2bf(b[1] * is); v[6] = f2bf(b[2] * is); v[7] = f2bf(b[3] * is);
  *(u16x8*)(Wp + (size_t)row * KTOT + KKAN + i0) = v;
}

// wavelet_w [o][i*7+g] -> bf16 W'[o][g*1024+i], LDS-staged for coalesced reads
__global__ void wkan_cast(const float* __restrict__ w, unsigned short* __restrict__ Wp) {
  __shared__ float row[KKAN];
  int orow = blockIdx.x;
  const float* src = w + (size_t)orow * KKAN;
  for (int c = threadIdx.x * 4; c < KKAN; c += 1024)
    *(f32x4*)&row[c] = *(const f32x4*)&src[c];
  __syncthreads();
  unsigned short* dst = Wp + (size_t)orow * KTOT;
  for (int r = threadIdx.x; r < 896; r += 256) {
    int g = r >> 7, i0 = (r & 127) << 3;
    u16x8 v;
#pragma unroll
    for (int j = 0; j < 8; j++) v[j] = f2bf(row[(i0 + j) * GG + g]);
    *(u16x8*)(dst + g * 1024 + i0) = v;
  }
}

// ---------------- activation expansion into A' [rows][8192] ----------------
__global__ void expand_kernel(const float* __restrict__ x,
                              const float* __restrict__ translation,
                              const float* __restrict__ scale,
                              unsigned short* __restrict__ Ap,
                              int row0, int nrows) {
  float tr[GG], iss[GG];
#pragma unroll
  for (int g = 0; g < GG; g++) {
    tr[g] = translation[g];
    float s = fabsf(scale[g]);
    iss[g] = 1.f / (s < 0.1f ? 0.1f : s);
  }
  int units = nrows * (INF / 8);
  int stride = gridDim.x * blockDim.x;
  for (int uu = blockIdx.x * blockDim.x + threadIdx.x; uu < units; uu += stride) {
    int nloc = uu >> 7;
    int i0 = (uu & 127) << 3;
    const f32x4* xp = (const f32x4*)(x + (size_t)(row0 + nloc) * INF + i0);
    f32x4 xa = xp[0], xb = xp[1];
    float xv[8] = {xa[0], xa[1], xa[2], xa[3], xb[0], xb[1], xb[2], xb[3]};
    u16x8 sb, kb[GG];
#pragma unroll
    for (int j = 0; j < 8; j++) {
      float xx = xv[j];
      float si = xx / (1.f + __expf(-xx));
      sb[j] = f2bf(si);
      float e2 = __expf(2.f * xx);
      float xn = 2.5f * (1.f - 2.f / (e2 + 1.f));
#pragma unroll
      for (int g = 0; g < GG; g++) {
        float xe = (xn - tr[g]) * iss[g];
        float t2 = xe * xe;
        float b = (1.f - t2) * __expf(-0.5f * t2);
        kb[g][j] = f2bf(b);
      }
    }
    unsigned short* rp = Ap + (size_t)nloc * KTOT;
    *(u16x8*)(rp + KKAN + i0) = sb;
#pragma unroll
    for (int g = 0; g < GG; g++) *(u16x8*)(rp + g * 1024 + i0) = kb[g];
  }
}

// ---------------- merged 256x256 8-phase GEMM, K = 8192 ----------------
static __device__ __forceinline__ void gload16(const unsigned short* g, unsigned short* l) {
  __builtin_amdgcn_global_load_lds(
      (const __attribute__((address_space(1))) unsigned int*)g,
      (__attribute__((address_space(3))) unsigned int*)l, 16, 0, 0);
}

#define SBAR  do { __builtin_amdgcn_sched_barrier(0); __builtin_amdgcn_s_barrier(); } while (0)
#define LGKM0 do { asm volatile("s_waitcnt lgkmcnt(0)" ::: "memory"); __builtin_amdgcn_sched_barrier(0); } while (0)
#define VM(N) asm volatile("s_waitcnt vmcnt(" #N ")" ::: "memory")

#define STAGE(gp, ld, bb, hh, tt) do { \
    const unsigned short* _s = (gp) + (size_t)((hh) * 128) * KTOT + (size_t)(tt) * 64; \
    unsigned short* _d = (ld) + (bb) * 16384 + (hh) * 8192; \
    gload16(_s, _d); \
    gload16(_s + (size_t)64 * KTOT, _d + 4096); \
  } while (0)

#define RDA(qq, bb) do { _Pragma("unroll") for (int i = 0; i < 4; ++i) { \
    const char* _p = pA + (bb) * 32768 + (qq) * 16384 + i * 2048; \
    af[i][0] = *(const bf16x8*)(_p + kx0); \
    af[i][1] = *(const bf16x8*)(_p + kx1); } } while (0)

#define RDB(dst, hh, bb) do { _Pragma("unroll") for (int j = 0; j < 2; ++j) { \
    const char* _p = pB + (bb) * 32768 + (hh) * 16384 + j * 2048; \
    dst[j][0] = *(const bf16x8*)(_p + kx0); \
    dst[j][1] = *(const bf16x8*)(_p + kx1); } } while (0)

#define MM(qq, pp, B) do { _Pragma("unroll") for (int i = 0; i < 4; ++i) \
    _Pragma("unroll") for (int j = 0; j < 2; ++j) \
    _Pragma("unroll") for (int k = 0; k < 2; ++k) \
      acc[qq][i][pp][j] = __builtin_amdgcn_mfma_f32_16x16x32_bf16(af[i][k], B[j][k], acc[qq][i][pp][j], 0, 0, 0); } while (0)

#define TILE(tt, bb, S1, S2, S3, S4, WAIT) do { \
    RDA(0, bb); RDB(bf0, 0, bb); \
    if (S1) STAGE(gB, ldB, (bb) ^ 1, 1, (tt) + 1); \
    asm volatile("s_waitcnt lgkmcnt(8)" ::: "memory"); \
    SBAR; LGKM0; \
    __builtin_amdgcn_s_setprio(1); MM(0, 0, bf0); __builtin_amdgcn_s_setprio(0); \
    SBAR; \
    RDB(bf1, 1, bb); \
    if (S2) STAGE(gA, ldA, bb, 0, (tt) + 2); \
    SBAR; LGKM0; \
    __builtin_amdgcn_s_setprio(1); MM(0, 1, bf1); __builtin_amdgcn_s_setprio(0); \
    SBAR; \
    RDA(1, bb); \
    if (S3) STAGE(gB, ldB, bb, 0, (tt) + 2); \
    SBAR; LGKM0; \
    __builtin_amdgcn_s_setprio(1); MM(1, 0, bf0); __builtin_amdgcn_s_setprio(0); \
    SBAR; \
    if (S4) STAGE(gA, ldA, bb, 1, (tt) + 2); \
    SBAR; \
    __builtin_amdgcn_s_setprio(1); MM(1, 1, bf1); __builtin_amdgcn_s_setprio(0); \
    WAIT; \
    SBAR; \
  } while (0)

__global__ __launch_bounds__(512, 2) void gemm8(
    const unsigned short* __restrict__ A,   // [mtiles*256][8192] bf16
    const unsigned short* __restrict__ W,   // [1024][8192] bf16
    const float* __restrict__ bias,
    const float* __restrict__ scal,
    float* __restrict__ out) {              // [mtiles*256][1024]
  __shared__ unsigned short lds[65536];

  int bid = blockIdx.x;
  int cpx = gridDim.x >> 3;
  int swz = (bid & 7) * cpx + (bid >> 3);
  int m0 = (swz >> 2) * 256;
  int n0 = (swz & 3) * 256;
  int tid = threadIdx.x;
  int wv = tid >> 6, l = tid & 63;
  int wr = wv >> 2, wc = wv & 3;

  float thr = scal[1], osc = scal[2];

  int rowq = tid >> 3;
  int swk = ((tid & 7) ^ (rowq & 7)) << 3;
  const unsigned short* gA = A + (size_t)(m0 + rowq) * KTOT + swk;
  const unsigned short* gB = W + (size_t)(n0 + rowq) * KTOT + swk;
  unsigned short* ldA = lds + wv * 512;
  unsigned short* ldB = lds + 32768 + wv * 512;

  int lr = l & 15;
  int kb = (l >> 4) << 4;
  int xr = (l & 7) << 4;
  int kx0 = kb ^ xr;
  int kx1 = (64 | kb) ^ xr;
  const char* pA = (const char*)lds + (wr * 64 + lr) * 128;
  const char* pB = (const char*)lds + 65536 + (wc * 32 + lr) * 128;

  bf16x8 af[4][2], bf0[2][2], bf1[2][2];
  f32x4 acc[2][4][2][2] = {};

  // prologue: tile 0 fully + {A0,B0,A1}(1) in flight -> wait keeps 6 outstanding
  STAGE(gA, ldA, 0, 0, 0);
  STAGE(gB, ldB, 0, 0, 0);
  STAGE(gA, ldA, 0, 1, 0);
  STAGE(gB, ldB, 0, 1, 0);
  STAGE(gA, ldA, 1, 0, 1);
  STAGE(gB, ldB, 1, 0, 1);
  STAGE(gA, ldA, 1, 1, 1);
  VM(6);
  SBAR;

  // ---- kan segment: tiles 0..111 ----
  for (int t = 0; t < 112; t += 2) {
    TILE(t,     0, 1, 1, 1, 1, VM(6));
    TILE(t + 1, 1, 1, 1, 1, 1, VM(6));
  }

  // ---- soft-threshold in-register at the boundary ----
#pragma unroll
  for (int q = 0; q < 2; ++q)
#pragma unroll
    for (int i = 0; i < 4; ++i)
#pragma unroll
      for (int p = 0; p < 2; ++p)
#pragma unroll
        for (int j = 0; j < 2; ++j)
#pragma unroll
          for (int e = 0; e < 4; ++e) {
            float v = acc[q][i][p][j][e];
            float a = fabsf(v) - thr;
            a = a > 0.f ? a : 0.f;
            acc[q][i][p][j][e] = v > 0.f ? a : -a;
          }

  // ---- base segment: tiles 112..127 ----
  for (int t = 112; t < 126; t += 2) {
    TILE(t,     0, 1, 1, 1, 1, VM(6));
    TILE(t + 1, 1, 1, 1, 1, 1, VM(6));
  }
  TILE(126, 0, 1, 0, 0, 0, VM(0));
  TILE(127, 1, 0, 0, 0, 0, (void)0);

  // epilogue: out = (acc + bias) * oscale
  int rr = m0 + wr * 64 + ((l >> 4) << 2);
  int cc = n0 + wc * 32 + lr;
#pragma unroll
  for (int q = 0; q < 2; ++q)
#pragma unroll
    for (int i = 0; i < 4; ++i)
#pragma unroll
      for (int p = 0; p < 2; ++p)
#pragma unroll
        for (int j = 0; j < 2; ++j) {
          int c = cc + p * 128 + j * 16;
          float bc = bias[c];
#pragma unroll
          for (int e = 0; e < 4; ++e) {
            int r = rr + q * 128 + i * 16 + e;
            out[(size_t)r * OUTF + c] = (acc[q][i][p][j][e] + bc) * osc;
          }
        }
}

// ---------------------------------------------------------------------------
extern "C" void kernel_launch(void* const* d_in, const int* in_sizes, int n_in,
                              void* d_out, int out_size, void* d_ws, size_t ws_size,
                              hipStream_t stream) {
  const float* x              = (const float*)d_in[0];
  const float* base_w         = (const float*)d_in[1];
  const float* base_b         = (const float*)d_in[2];
  const float* u              = (const float*)d_in[3];
  const float* translation    = (const float*)d_in[4];
  const float* scale          = (const float*)d_in[5];
  const float* wavelet_w      = (const float*)d_in[6];
  const float* soft_threshold = (const float*)d_in[7];
  const float* output_scale   = (const float*)d_in[8];
  float* out = (float*)d_out;

  char* ws = (char*)d_ws;
  float* t_vec = (float*)ws;
  float* s_vec = t_vec + 1024;
  float* scal  = s_vec + 1024;
  unsigned short* Wp = (unsigned short*)(ws + 16384);                       // 16 MB
  char* apanel = ws + 16384 + (size_t)KTOT * OUTF * 2;

  size_t fixed = 16384 + (size_t)KTOT * OUTF * 2;
  size_t avail = ws_size > fixed ? ws_size - fixed : 0;
  long mc = (long)(avail / ((size_t)KTOT * 2));
  if (mc > NROWS) mc = NROWS;
  mc -= mc % 512;
  if (mc < 512) mc = 512;

  mv_wt_u<<<1024, 256, 0, stream>>>(base_w, u, t_vec);
  mv_w_t<<<1024, 256, 0, stream>>>(base_w, t_vec, s_vec);
  sigma_finish<<<1, 256, 0, stream>>>(t_vec, s_vec, soft_threshold, output_scale, scal);

  wsn_cast<<<512, 256, 0, stream>>>(base_w, scal, Wp);
  wkan_cast<<<1024, 256, 0, stream>>>(wavelet_w, Wp);

  unsigned short* Ap = (unsigned short*)apanel;

  for (long r0 = 0; r0 < NROWS; r0 += mc) {
    long nr = (NROWS - r0 < mc) ? (NROWS - r0) : mc;
    expand_kernel<<<2048, 256, 0, stream>>>(x, translation, scale, Ap, (int)r0, (int)nr);
    int mt = (int)(nr / 256);
    gemm8<<<mt * 4, 512, 0, stream>>>(Ap, Wp, base_b, scal, out + (size_t)r0 * OUTF);
  }
}

// Round 4
// 422.422 us; speedup vs baseline: 1.6106x; 1.1288x over previous
//
#include <hip/hip_runtime.h>
#include <math.h>

// ---------------------------------------------------------------------------
// out = (silu(x) @ (W/sigma)^T + b  +  softthr(basis(x) @ Ww^T)) * oscale
// bf16 MFMA, 256x256 8-phase counted-vmcnt schedule.
// Merged K = [kan 7168 | base 1024] = 8192.
// If ws fits all rows: single merged gemm (softthr in-register at boundary).
// Else: row-chunks with K-split gemm (2x parallelism) + combine kernel.
// ---------------------------------------------------------------------------

typedef __attribute__((ext_vector_type(4))) float  f32x4;
typedef __attribute__((ext_vector_type(8))) __bf16 bf16x8;
typedef __attribute__((ext_vector_type(8))) unsigned short u16x8;

#define NROWS 16384
#define INF   1024
#define OUTF  1024
#define GG    7
#define KKAN  7168
#define KTOT  8192

static __device__ __forceinline__ unsigned short f2bf(float f) {
  union { float f; unsigned int u; } v; v.f = f;
  unsigned int r = v.u + 0x7fffu + ((v.u >> 16) & 1u);  // RNE
  return (unsigned short)(r >> 16);
}

// ---------------- sigma (spectral norm) ----------------
__global__ void mv_wt_u(const float* __restrict__ W, const float* __restrict__ u,
                        float* __restrict__ t) {
  int j = blockIdx.x;
  int tid = threadIdx.x;
  float p = 0.f;
  for (int i = tid; i < OUTF; i += 256) p += W[(size_t)i * INF + j] * u[i];
  __shared__ float red[256];
  red[tid] = p; __syncthreads();
  for (int s = 128; s > 0; s >>= 1) { if (tid < s) red[tid] += red[tid + s]; __syncthreads(); }
  if (tid == 0) t[j] = red[0];
}

__global__ void mv_w_t(const float* __restrict__ W, const float* __restrict__ t,
                       float* __restrict__ s) {
  int i = blockIdx.x;
  int tid = threadIdx.x;
  float p = 0.f;
  for (int j = tid; j < INF; j += 256) p += W[(size_t)i * INF + j] * t[j];
  __shared__ float red[256];
  red[tid] = p; __syncthreads();
  for (int k = 128; k > 0; k >>= 1) { if (tid < k) red[tid] += red[tid + k]; __syncthreads(); }
  if (tid == 0) s[i] = red[0];
}

__global__ void sigma_finish(const float* __restrict__ t, const float* __restrict__ s,
                             const float* __restrict__ st, const float* __restrict__ os,
                             float* __restrict__ scal) {
  __shared__ float r1[256], r2[256];
  int tid = threadIdx.x;
  float p1 = 0.f, p2 = 0.f;
  for (int i = tid; i < 1024; i += 256) { float a = t[i]; p1 += a * a; float b = s[i]; p2 += b * b; }
  r1[tid] = p1; r2[tid] = p2; __syncthreads();
  for (int k = 128; k > 0; k >>= 1) { if (tid < k) { r1[tid] += r1[tid + k]; r2[tid] += r2[tid + k]; } __syncthreads(); }
  if (tid == 0) {
    float nt = sqrtf(r1[0]);
    float ns = sqrtf(r2[0]);
    float nq = ns / (nt + 1e-12f);
    float sigma = nq * nq / (nq + 1e-12f);
    scal[0] = 1.f / sigma;
    scal[1] = log1pf(__expf(st[0]));
    scal[2] = os[0];
  }
}

// ---------------- weight casts into W' [1024][8192] ----------------
__global__ void wsn_cast(const float* __restrict__ w, const float* __restrict__ scal,
                         unsigned short* __restrict__ Wp) {
  float is = scal[0];
  int idx = blockIdx.x * 256 + threadIdx.x;
  int row = idx >> 7, i0 = (idx & 127) << 3;
  const f32x4* p = (const f32x4*)(w + (size_t)row * INF + i0);
  f32x4 a = p[0], b = p[1];
  u16x8 v;
  v[0] = f2bf(a[0] * is); v[1] = f2bf(a[1] * is); v[2] = f2bf(a[2] * is); v[3] = f2bf(a[3] * is);
  v[4] = f2bf(b[0] * is); v[5] = f2bf(b[1] * is); v[6] = f2bf(b[2] * is); v[7] = f2bf(b[3] * is);
  *(u16x8*)(Wp + (size_t)row * KTOT + KKAN + i0) = v;
}

__global__ void wkan_cast(const float* __restrict__ w, unsigned short* __restrict__ Wp) {
  __shared__ float row[KKAN];
  int orow = blockIdx.x;
  const float* src = w + (size_t)orow * KKAN;
  for (int c = threadIdx.x * 4; c < KKAN; c += 1024)
    *(f32x4*)&row[c] = *(const f32x4*)&src[c];
  __syncthreads();
  unsigned short* dst = Wp + (size_t)orow * KTOT;
  for (int r = threadIdx.x; r < 896; r += 256) {
    int g = r >> 7, i0 = (r & 127) << 3;
    u16x8 v;
#pragma unroll
    for (int j = 0; j < 8; j++) v[j] = f2bf(row[(i0 + j) * GG + g]);
    *(u16x8*)(dst + g * 1024 + i0) = v;
  }
}

// ---------------- activation expansion into A' [rows][8192] ----------------
__global__ void expand_kernel(const float* __restrict__ x,
                              const float* __restrict__ translation,
                              const float* __restrict__ scale,
                              unsigned short* __restrict__ Ap,
                              int row0, int nrows) {
  float tr[GG], iss[GG];
#pragma unroll
  for (int g = 0; g < GG; g++) {
    tr[g] = translation[g];
    float s = fabsf(scale[g]);
    iss[g] = 1.f / (s < 0.1f ? 0.1f : s);
  }
  int units = nrows * (INF / 8);
  int stride = gridDim.x * blockDim.x;
  for (int uu = blockIdx.x * blockDim.x + threadIdx.x; uu < units; uu += stride) {
    int nloc = uu >> 7;
    int i0 = (uu & 127) << 3;
    const f32x4* xp = (const f32x4*)(x + (size_t)(row0 + nloc) * INF + i0);
    f32x4 xa = xp[0], xb = xp[1];
    float xv[8] = {xa[0], xa[1], xa[2], xa[3], xb[0], xb[1], xb[2], xb[3]};
    u16x8 sb, kb[GG];
#pragma unroll
    for (int j = 0; j < 8; j++) {
      float xx = xv[j];
      float si = xx / (1.f + __expf(-xx));
      sb[j] = f2bf(si);
      float e2 = __expf(2.f * xx);
      float xn = 2.5f * (1.f - 2.f / (e2 + 1.f));
#pragma unroll
      for (int g = 0; g < GG; g++) {
        float xe = (xn - tr[g]) * iss[g];
        float t2 = xe * xe;
        float b = (1.f - t2) * __expf(-0.5f * t2);
        kb[g][j] = f2bf(b);
      }
    }
    unsigned short* rp = Ap + (size_t)nloc * KTOT;
    *(u16x8*)(rp + KKAN + i0) = sb;
#pragma unroll
    for (int g = 0; g < GG; g++) *(u16x8*)(rp + g * 1024 + i0) = kb[g];
  }
}

// ---------------- GEMM machinery ----------------
static __device__ __forceinline__ void gload16(const unsigned short* g, unsigned short* l) {
  __builtin_amdgcn_global_load_lds(
      (const __attribute__((address_space(1))) unsigned int*)g,
      (__attribute__((address_space(3))) unsigned int*)l, 16, 0, 0);
}

#define SBAR  do { __builtin_amdgcn_sched_barrier(0); __builtin_amdgcn_s_barrier(); } while (0)
#define LGKM0 do { asm volatile("s_waitcnt lgkmcnt(0)" ::: "memory"); __builtin_amdgcn_sched_barrier(0); } while (0)
#define VM(N) asm volatile("s_waitcnt vmcnt(" #N ")" ::: "memory")

#define STAGE(gp, ld, bb, hh, tt) do { \
    const unsigned short* _s = (gp) + (size_t)((hh) * 128) * KTOT + (size_t)(tt) * 64; \
    unsigned short* _d = (ld) + (bb) * 16384 + (hh) * 8192; \
    gload16(_s, _d); \
    gload16(_s + (size_t)64 * KTOT, _d + 4096); \
  } while (0)

#define RDA(qq, bb) do { _Pragma("unroll") for (int i = 0; i < 4; ++i) { \
    const char* _p = pA + (bb) * 32768 + (qq) * 16384 + i * 2048; \
    af[i][0] = *(const bf16x8*)(_p + kx0); \
    af[i][1] = *(const bf16x8*)(_p + kx1); } } while (0)

#define RDB(dst, hh, bb) do { _Pragma("unroll") for (int j = 0; j < 2; ++j) { \
    const char* _p = pB + (bb) * 32768 + (hh) * 16384 + j * 2048; \
    dst[j][0] = *(const bf16x8*)(_p + kx0); \
    dst[j][1] = *(const bf16x8*)(_p + kx1); } } while (0)

#define MM(ACC, qq, pp, B) do { _Pragma("unroll") for (int i = 0; i < 4; ++i) \
    _Pragma("unroll") for (int j = 0; j < 2; ++j) \
    _Pragma("unroll") for (int k = 0; k < 2; ++k) \
      ACC[qq][i][pp][j] = __builtin_amdgcn_mfma_f32_16x16x32_bf16(af[i][k], B[j][k], ACC[qq][i][pp][j], 0, 0, 0); } while (0)

#define TILE(ACC, tt, bb, S1, S2, S3, S4, WAIT) do { \
    RDA(0, bb); RDB(bf0, 0, bb); \
    if (S1) STAGE(gB, ldB, (bb) ^ 1, 1, (tt) + 1); \
    asm volatile("s_waitcnt lgkmcnt(8)" ::: "memory"); \
    SBAR; LGKM0; \
    __builtin_amdgcn_s_setprio(1); MM(ACC, 0, 0, bf0); __builtin_amdgcn_s_setprio(0); \
    SBAR; \
    RDB(bf1, 1, bb); \
    if (S2) STAGE(gA, ldA, bb, 0, (tt) + 2); \
    SBAR; LGKM0; \
    __builtin_amdgcn_s_setprio(1); MM(ACC, 0, 1, bf1); __builtin_amdgcn_s_setprio(0); \
    SBAR; \
    RDA(1, bb); \
    if (S3) STAGE(gB, ldB, bb, 0, (tt) + 2); \
    SBAR; LGKM0; \
    __builtin_amdgcn_s_setprio(1); MM(ACC, 1, 0, bf0); __builtin_amdgcn_s_setprio(0); \
    SBAR; \
    if (S4) STAGE(gA, ldA, bb, 1, (tt) + 2); \
    SBAR; \
    __builtin_amdgcn_s_setprio(1); MM(ACC, 1, 1, bf1); __builtin_amdgcn_s_setprio(0); \
    WAIT; \
    SBAR; \
  } while (0)

#define PROLOGUE(T0) do { \
    STAGE(gA, ldA, 0, 0, (T0)); \
    STAGE(gB, ldB, 0, 0, (T0)); \
    STAGE(gA, ldA, 0, 1, (T0)); \
    STAGE(gB, ldB, 0, 1, (T0)); \
    STAGE(gA, ldA, 1, 0, (T0) + 1); \
    STAGE(gB, ldB, 1, 0, (T0) + 1); \
    STAGE(gA, ldA, 1, 1, (T0) + 1); \
    VM(6); \
    SBAR; \
  } while (0)

// store one acc group: ST(ACC, dst_expr) where dst_expr uses r,c
#define STACC(ACC, STMT) do { \
    _Pragma("unroll") for (int q = 0; q < 2; ++q) \
    _Pragma("unroll") for (int i = 0; i < 4; ++i) \
    _Pragma("unroll") for (int p = 0; p < 2; ++p) \
    _Pragma("unroll") for (int j = 0; j < 2; ++j) { \
      int c = cc + p * 128 + j * 16; \
      _Pragma("unroll") for (int e = 0; e < 4; ++e) { \
        int r = rr + q * 128 + i * 16 + e; \
        float v = ACC[q][i][p][j][e]; \
        STMT; \
      } \
    } \
  } while (0)

// ---- merged single-dispatch kernel (ws fits all rows) ----
__global__ __launch_bounds__(512, 2) void gemm_merged(
    const unsigned short* __restrict__ A, const unsigned short* __restrict__ W,
    const float* __restrict__ bias, const float* __restrict__ scal,
    float* __restrict__ out) {
  __shared__ unsigned short lds[65536];
  int bid = blockIdx.x;
  int cpx = gridDim.x >> 3;
  int swz = (bid & 7) * cpx + (bid >> 3);
  int m0 = (swz >> 2) * 256;
  int n0 = (swz & 3) * 256;
  int tid = threadIdx.x;
  int wv = tid >> 6, l = tid & 63;
  int wr = wv >> 2, wc = wv & 3;
  float thr = scal[1], osc = scal[2];

  int rowq = tid >> 3;
  int swk = ((tid & 7) ^ (rowq & 7)) << 3;
  const unsigned short* gA = A + (size_t)(m0 + rowq) * KTOT + swk;
  const unsigned short* gB = W + (size_t)(n0 + rowq) * KTOT + swk;
  unsigned short* ldA = lds + wv * 512;
  unsigned short* ldB = lds + 32768 + wv * 512;

  int lr = l & 15;
  int kb = (l >> 4) << 4;
  int xr = (l & 7) << 4;
  int kx0 = kb ^ xr;
  int kx1 = (64 | kb) ^ xr;
  const char* pA = (const char*)lds + (wr * 64 + lr) * 128;
  const char* pB = (const char*)lds + 65536 + (wc * 32 + lr) * 128;

  bf16x8 af[4][2], bf0[2][2], bf1[2][2];
  f32x4 acc[2][4][2][2] = {};

  PROLOGUE(0);
  for (int t = 0; t < 112; t += 2) {
    TILE(acc, t,     0, 1, 1, 1, 1, VM(6));
    TILE(acc, t + 1, 1, 1, 1, 1, 1, VM(6));
  }
#pragma unroll
  for (int q = 0; q < 2; ++q)
#pragma unroll
    for (int i = 0; i < 4; ++i)
#pragma unroll
      for (int p = 0; p < 2; ++p)
#pragma unroll
        for (int j = 0; j < 2; ++j)
#pragma unroll
          for (int e = 0; e < 4; ++e) {
            float v = acc[q][i][p][j][e];
            float a = fabsf(v) - thr;
            a = a > 0.f ? a : 0.f;
            acc[q][i][p][j][e] = v > 0.f ? a : -a;
          }
  for (int t = 112; t < 126; t += 2) {
    TILE(acc, t,     0, 1, 1, 1, 1, VM(6));
    TILE(acc, t + 1, 1, 1, 1, 1, 1, VM(6));
  }
  TILE(acc, 126, 0, 1, 0, 0, 0, VM(0));
  TILE(acc, 127, 1, 0, 0, 0, 0, (void)0);

  int rr = m0 + wr * 64 + ((l >> 4) << 2);
  int cc = n0 + wc * 32 + lr;
  STACC(acc, { float bc = bias[c]; out[(size_t)r * OUTF + c] = (v + bc) * osc; });
}

// ---- K-split kernel: half1 -> pK1; half2 -> pK2 + (base+bias)->out ----
__global__ __launch_bounds__(512, 2) void gemm_split(
    const unsigned short* __restrict__ A, const unsigned short* __restrict__ W,
    const float* __restrict__ bias,
    float* __restrict__ pK1, float* __restrict__ pK2,
    float* __restrict__ out) {
  __shared__ unsigned short lds[65536];
  int bid = blockIdx.x;
  int cpx = gridDim.x >> 3;
  int swz = (bid & 7) * cpx + (bid >> 3);
  int halfg = gridDim.x >> 1;
  int kh = swz >= halfg ? 1 : 0;
  int j0 = swz - kh * halfg;
  int m0 = (j0 >> 2) * 256;
  int n0 = (j0 & 3) * 256;
  int tid = threadIdx.x;
  int wv = tid >> 6, l = tid & 63;
  int wr = wv >> 2, wc = wv & 3;

  int rowq = tid >> 3;
  int swk = ((tid & 7) ^ (rowq & 7)) << 3;
  const unsigned short* gA = A + (size_t)(m0 + rowq) * KTOT + swk;
  const unsigned short* gB = W + (size_t)(n0 + rowq) * KTOT + swk;
  unsigned short* ldA = lds + wv * 512;
  unsigned short* ldB = lds + 32768 + wv * 512;

  int lr = l & 15;
  int kb = (l >> 4) << 4;
  int xr = (l & 7) << 4;
  int kx0 = kb ^ xr;
  int kx1 = (64 | kb) ^ xr;
  const char* pA = (const char*)lds + (wr * 64 + lr) * 128;
  const char* pB = (const char*)lds + 65536 + (wc * 32 + lr) * 128;

  bf16x8 af[4][2], bf0[2][2], bf1[2][2];
  int rr = m0 + wr * 64 + ((l >> 4) << 2);
  int cc = n0 + wc * 32 + lr;

  if (kh == 0) {
    // tiles 0..63: kan partial 1
    f32x4 acc[2][4][2][2] = {};
    PROLOGUE(0);
    for (int t = 0; t < 62; t += 2) {
      TILE(acc, t,     0, 1, 1, 1, 1, VM(6));
      TILE(acc, t + 1, 1, 1, 1, 1, 1, VM(6));
    }
    TILE(acc, 62, 0, 1, 0, 0, 0, VM(0));
    TILE(acc, 63, 1, 0, 0, 0, 0, (void)0);
    STACC(acc, { pK1[(size_t)r * OUTF + c] = v; });
  } else {
    // tiles 64..111: kan partial 2; tiles 112..127: base -> out
    f32x4 accK[2][4][2][2] = {};
    f32x4 accB[2][4][2][2] = {};
    PROLOGUE(64);
    for (int t = 64; t < 112; t += 2) {
      TILE(accK, t,     0, 1, 1, 1, 1, VM(6));
      TILE(accK, t + 1, 1, 1, 1, 1, 1, VM(6));
    }
    for (int t = 112; t < 126; t += 2) {
      TILE(accB, t,     0, 1, 1, 1, 1, VM(6));
      TILE(accB, t + 1, 1, 1, 1, 1, 1, VM(6));
    }
    TILE(accB, 126, 0, 1, 0, 0, 0, VM(0));
    TILE(accB, 127, 1, 0, 0, 0, 0, (void)0);
    STACC(accK, { pK2[(size_t)r * OUTF + c] = v; });
    STACC(accB, { float bc = bias[c]; out[(size_t)r * OUTF + c] = v + bc; });
  }
}

// ---- combine: out = (softthr(pK1+pK2) + out) * osc ----
__global__ void combine_kernel(const float* __restrict__ pK1, const float* __restrict__ pK2,
                               const float* __restrict__ scal, float* __restrict__ out,
                               int nvec) {
  float thr = scal[1], osc = scal[2];
  int stride = gridDim.x * blockDim.x;
  for (int i = blockIdx.x * blockDim.x + threadIdx.x; i < nvec; i += stride) {
    f32x4 a = ((const f32x4*)pK1)[i];
    f32x4 b = ((const f32x4*)pK2)[i];
    f32x4 o = ((const f32x4*)out)[i];
    f32x4 r;
#pragma unroll
    for (int e = 0; e < 4; ++e) {
      float v = a[e] + b[e];
      float s = fabsf(v) - thr;
      s = s > 0.f ? s : 0.f;
      float k = v > 0.f ? s : -s;
      r[e] = (o[e] + k) * osc;
    }
    ((f32x4*)out)[i] = r;
  }
}

// ---------------------------------------------------------------------------
extern "C" void kernel_launch(void* const* d_in, const int* in_sizes, int n_in,
                              void* d_out, int out_size, void* d_ws, size_t ws_size,
                              hipStream_t stream) {
  const float* x              = (const float*)d_in[0];
  const float* base_w         = (const float*)d_in[1];
  const float* base_b         = (const float*)d_in[2];
  const float* u              = (const float*)d_in[3];
  const float* translation    = (const float*)d_in[4];
  const float* scale          = (const float*)d_in[5];
  const float* wavelet_w      = (const float*)d_in[6];
  const float* soft_threshold = (const float*)d_in[7];
  const float* output_scale   = (const float*)d_in[8];
  float* out = (float*)d_out;

  char* ws = (char*)d_ws;
  float* t_vec = (float*)ws;
  float* s_vec = t_vec + 1024;
  float* scal  = s_vec + 1024;
  unsigned short* Wp = (unsigned short*)(ws + 16384);    // 16 MB
  char* dynbuf = ws + 16384 + (size_t)KTOT * OUTF * 2;

  size_t fixed = 16384 + (size_t)KTOT * OUTF * 2;
  size_t avail = ws_size > fixed ? ws_size - fixed : 0;

  mv_wt_u<<<1024, 256, 0, stream>>>(base_w, u, t_vec);
  mv_w_t<<<1024, 256, 0, stream>>>(base_w, t_vec, s_vec);
  sigma_finish<<<1, 256, 0, stream>>>(t_vec, s_vec, soft_threshold, output_scale, scal);
  wsn_cast<<<512, 256, 0, stream>>>(base_w, scal, Wp);
  wkan_cast<<<1024, 256, 0, stream>>>(wavelet_w, Wp);

  const size_t ROW_M = (size_t)KTOT * 2;            // A' bytes per row (merged)
  const size_t ROW_S = (size_t)KTOT * 2 + 8192;     // + pK1,pK2 f32 per row

  if (avail >= (size_t)NROWS * ROW_M) {
    // single merged dispatch, full grid
    unsigned short* Ap = (unsigned short*)dynbuf;
    expand_kernel<<<2048, 256, 0, stream>>>(x, translation, scale, Ap, 0, NROWS);
    gemm_merged<<<(NROWS / 256) * 4, 512, 0, stream>>>(Ap, Wp, base_b, scal, out);
  } else {
    int nch = (int)(((size_t)NROWS * ROW_S + avail - 1) / (avail > 0 ? avail : 1));
    if (nch < 2) nch = 2;
    long mc = ((NROWS + nch - 1) / nch + 255) & ~255L;
    while (mc > 256 && (size_t)mc * ROW_S > avail) mc -= 256;
    if (mc < 256) mc = 256;   // assume ws >= ~25 MB

    unsigned short* Ap = (unsigned short*)dynbuf;
    float* pK1 = (float*)(dynbuf + (size_t)mc * KTOT * 2);
    float* pK2 = pK1 + (size_t)mc * OUTF;

    for (long r0 = 0; r0 < NROWS; r0 += mc) {
      long nr = (NROWS - r0 < mc) ? (NROWS - r0) : mc;
      expand_kernel<<<2048, 256, 0, stream>>>(x, translation, scale, Ap, (int)r0, (int)nr);
      int jobs = (int)(nr / 256) * 4;
      float* outc = out + (size_t)r0 * OUTF;
      gemm_split<<<jobs * 2, 512, 0, stream>>>(Ap, Wp, base_b, pK1, pK2, outc);
      combine_kernel<<<2048, 256, 0, stream>>>(pK1, pK2, scal, outc, (int)(nr * OUTF / 4));
    }
  }
}

// Round 5
// 363.147 us; speedup vs baseline: 1.8734x; 1.1632x over previous
//
#include <hip/hip_runtime.h>
#include <math.h>

// ---------------------------------------------------------------------------
// out = (silu(x) @ (W/sigma)^T + b  +  softthr(basis(x) @ Ww^T)) * oscale
// Merged K = [kan 7168 | base 1024] = 8192, bf16 MFMA.
// BM=256 x BN=128 tiles, BK=64, 8 waves (4M x 2N, 64x64 wave tiles),
// 4-phase/K-tile counted-vmcnt schedule, softthr in-register at tile 112.
// Row-chunked to fit ws; each chunk = full 256-block grid.
// ---------------------------------------------------------------------------

typedef __attribute__((ext_vector_type(4))) float  f32x4;
typedef __attribute__((ext_vector_type(8))) __bf16 bf16x8;
typedef __attribute__((ext_vector_type(8))) unsigned short u16x8;

#define NROWS 16384
#define INF   1024
#define OUTF  1024
#define GG    7
#define KKAN  7168
#define KTOT  8192

static __device__ __forceinline__ unsigned short f2bf(float f) {
  union { float f; unsigned int u; } v; v.f = f;
  unsigned int r = v.u + 0x7fffu + ((v.u >> 16) & 1u);  // RNE
  return (unsigned short)(r >> 16);
}

// ---------------- sigma (spectral norm) ----------------
__global__ void mv_wt_u(const float* __restrict__ W, const float* __restrict__ u,
                        float* __restrict__ t) {
  int j = blockIdx.x;
  int tid = threadIdx.x;
  float p = 0.f;
  for (int i = tid; i < OUTF; i += 256) p += W[(size_t)i * INF + j] * u[i];
  __shared__ float red[256];
  red[tid] = p; __syncthreads();
  for (int s = 128; s > 0; s >>= 1) { if (tid < s) red[tid] += red[tid + s]; __syncthreads(); }
  if (tid == 0) t[j] = red[0];
}

__global__ void mv_w_t(const float* __restrict__ W, const float* __restrict__ t,
                       float* __restrict__ s) {
  int i = blockIdx.x;
  int tid = threadIdx.x;
  float p = 0.f;
  for (int j = tid; j < INF; j += 256) p += W[(size_t)i * INF + j] * t[j];
  __shared__ float red[256];
  red[tid] = p; __syncthreads();
  for (int k = 128; k > 0; k >>= 1) { if (tid < k) red[tid] += red[tid + k]; __syncthreads(); }
  if (tid == 0) s[i] = red[0];
}

__global__ void sigma_finish(const float* __restrict__ t, const float* __restrict__ s,
                             const float* __restrict__ st, const float* __restrict__ os,
                             float* __restrict__ scal) {
  __shared__ float r1[256], r2[256];
  int tid = threadIdx.x;
  float p1 = 0.f, p2 = 0.f;
  for (int i = tid; i < 1024; i += 256) { float a = t[i]; p1 += a * a; float b = s[i]; p2 += b * b; }
  r1[tid] = p1; r2[tid] = p2; __syncthreads();
  for (int k = 128; k > 0; k >>= 1) { if (tid < k) { r1[tid] += r1[tid + k]; r2[tid] += r2[tid + k]; } __syncthreads(); }
  if (tid == 0) {
    float nt = sqrtf(r1[0]);
    float ns = sqrtf(r2[0]);
    float nq = ns / (nt + 1e-12f);
    float sigma = nq * nq / (nq + 1e-12f);
    scal[0] = 1.f / sigma;
    scal[1] = log1pf(__expf(st[0]));
    scal[2] = os[0];
  }
}

// ---------------- weight casts into W' [1024][8192] ----------------
__global__ void wsn_cast(const float* __restrict__ w, const float* __restrict__ scal,
                         unsigned short* __restrict__ Wp) {
  float is = scal[0];
  int idx = blockIdx.x * 256 + threadIdx.x;
  int row = idx >> 7, i0 = (idx & 127) << 3;
  const f32x4* p = (const f32x4*)(w + (size_t)row * INF + i0);
  f32x4 a = p[0], b = p[1];
  u16x8 v;
  v[0] = f2bf(a[0] * is); v[1] = f2bf(a[1] * is); v[2] = f2bf(a[2] * is); v[3] = f2bf(a[3] * is);
  v[4] = f2bf(b[0] * is); v[5] = f2bf(b[1] * is); v[6] = f2bf(b[2] * is); v[7] = f2bf(b[3] * is);
  *(u16x8*)(Wp + (size_t)row * KTOT + KKAN + i0) = v;
}

__global__ void wkan_cast(const float* __restrict__ w, unsigned short* __restrict__ Wp) {
  __shared__ float row[KKAN];
  int orow = blockIdx.x;
  const float* src = w + (size_t)orow * KKAN;
  for (int c = threadIdx.x * 4; c < KKAN; c += 1024)
    *(f32x4*)&row[c] = *(const f32x4*)&src[c];
  __syncthreads();
  unsigned short* dst = Wp + (size_t)orow * KTOT;
  for (int r = threadIdx.x; r < 896; r += 256) {
    int g = r >> 7, i0 = (r & 127) << 3;
    u16x8 v;
#pragma unroll
    for (int j = 0; j < 8; j++) v[j] = f2bf(row[(i0 + j) * GG + g]);
    *(u16x8*)(dst + g * 1024 + i0) = v;
  }
}

// ---------------- activation expansion into A' [rows][8192] ----------------
__global__ void expand_kernel(const float* __restrict__ x,
                              const float* __restrict__ translation,
                              const float* __restrict__ scale,
                              unsigned short* __restrict__ Ap,
                              int row0, int nrows) {
  float tr[GG], iss[GG];
#pragma unroll
  for (int g = 0; g < GG; g++) {
    tr[g] = translation[g];
    float s = fabsf(scale[g]);
    iss[g] = 1.f / (s < 0.1f ? 0.1f : s);
  }
  int units = nrows * (INF / 8);
  int stride = gridDim.x * blockDim.x;
  for (int uu = blockIdx.x * blockDim.x + threadIdx.x; uu < units; uu += stride) {
    int nloc = uu >> 7;
    int i0 = (uu & 127) << 3;
    const f32x4* xp = (const f32x4*)(x + (size_t)(row0 + nloc) * INF + i0);
    f32x4 xa = xp[0], xb = xp[1];
    float xv[8] = {xa[0], xa[1], xa[2], xa[3], xb[0], xb[1], xb[2], xb[3]};
    u16x8 sb, kb[GG];
#pragma unroll
    for (int j = 0; j < 8; j++) {
      float xx = xv[j];
      float si = xx / (1.f + __expf(-xx));
      sb[j] = f2bf(si);
      float e2 = __expf(2.f * xx);
      float xn = 2.5f * (1.f - 2.f / (e2 + 1.f));
#pragma unroll
      for (int g = 0; g < GG; g++) {
        float xe = (xn - tr[g]) * iss[g];
        float t2 = xe * xe;
        float b = (1.f - t2) * __expf(-0.5f * t2);
        kb[g][j] = f2bf(b);
      }
    }
    unsigned short* rp = Ap + (size_t)nloc * KTOT;
    *(u16x8*)(rp + KKAN + i0) = sb;
#pragma unroll
    for (int g = 0; g < GG; g++) *(u16x8*)(rp + g * 1024 + i0) = kb[g];
  }
}

// ---------------- GEMM machinery ----------------
static __device__ __forceinline__ void gload16(const unsigned short* g, unsigned short* l) {
  __builtin_amdgcn_global_load_lds(
      (const __attribute__((address_space(1))) unsigned int*)g,
      (__attribute__((address_space(3))) unsigned int*)l, 16, 0, 0);
}

#define SBAR  do { __builtin_amdgcn_sched_barrier(0); __builtin_amdgcn_s_barrier(); } while (0)
#define LGKM0 do { asm volatile("s_waitcnt lgkmcnt(0)" ::: "memory"); __builtin_amdgcn_sched_barrier(0); } while (0)
#define VM(N) asm volatile("s_waitcnt vmcnt(" #N ")" ::: "memory")

// A half-tile stage: 128 rows x 64 k (2 gload16/thread)
#define STAGE_A(bb, hh, tt) do { \
    const unsigned short* _s = gA + (size_t)((hh) * 128) * KTOT + (size_t)(tt) * 64; \
    unsigned short* _d = ldA + (bb) * 16384 + (hh) * 8192; \
    gload16(_s, _d); \
    gload16(_s + (size_t)64 * KTOT, _d + 4096); \
  } while (0)

// B tile stage: 128 rows x 64 k
#define STAGE_B(bb, tt) do { \
    const unsigned short* _s = gB + (size_t)(tt) * 64; \
    unsigned short* _d = ldB + (bb) * 8192; \
    gload16(_s, _d); \
    gload16(_s + (size_t)64 * KTOT, _d + 4096); \
  } while (0)

#define RD_A(bb, kx) do { _Pragma("unroll") for (int i = 0; i < 4; ++i) \
    af[i] = *(const bf16x8*)(pA + (bb) * 32768 + i * 2048 + (kx)); } while (0)

#define RD_B(bb, jg, kx) do { _Pragma("unroll") for (int jj = 0; jj < 2; ++jj) \
    bf[jj] = *(const bf16x8*)(pB + (bb) * 16384 + ((jg) * 2 + jj) * 2048 + (kx)); } while (0)

#define MMp(jg) do { _Pragma("unroll") for (int i = 0; i < 4; ++i) \
    _Pragma("unroll") for (int jj = 0; jj < 2; ++jj) \
      acc[i][(jg) * 2 + jj] = __builtin_amdgcn_mfma_f32_16x16x32_bf16(af[i], bf[jj], acc[i][(jg) * 2 + jj], 0, 0, 0); } while (0)

// one K-tile, 4 phases; stages: B(t+1) at ph1 (region drained end of prev ph4),
// A(t+2) at ph4 (region drained end of ph3). Steady-state vmcnt(4).
#define TILE(tt, bb, SB, SA, WAIT) do { \
    RD_A(bb, kx0); RD_B(bb, 0, kx0); \
    if (SB) STAGE_B((bb) ^ 1, (tt) + 1); \
    SBAR; LGKM0; \
    __builtin_amdgcn_s_setprio(1); MMp(0); __builtin_amdgcn_s_setprio(0); \
    SBAR; \
    RD_B(bb, 1, kx0); \
    SBAR; LGKM0; \
    __builtin_amdgcn_s_setprio(1); MMp(1); __builtin_amdgcn_s_setprio(0); \
    SBAR; \
    RD_A(bb, kx1); RD_B(bb, 0, kx1); \
    SBAR; LGKM0; \
    __builtin_amdgcn_s_setprio(1); MMp(0); __builtin_amdgcn_s_setprio(0); \
    SBAR; \
    RD_B(bb, 1, kx1); \
    if (SA) { STAGE_A(bb, 0, (tt) + 2); STAGE_A(bb, 1, (tt) + 2); } \
    SBAR; LGKM0; \
    __builtin_amdgcn_s_setprio(1); MMp(1); __builtin_amdgcn_s_setprio(0); \
    WAIT; \
    SBAR; \
  } while (0)

// BM=256 x BN=128, 8 waves (4M x 2N), K = 8192 merged, softthr at tile 112
__global__ __launch_bounds__(512, 2) void gemm_k(
    const unsigned short* __restrict__ A,   // [mt*256][8192] bf16
    const unsigned short* __restrict__ W,   // [1024][8192] bf16
    const float* __restrict__ bias,
    const float* __restrict__ scal,
    float* __restrict__ out) {              // [mt*256][1024]
  __shared__ unsigned short lds[49152];     // A: 2x16384, B at 32768: 2x8192

  int bid = blockIdx.x;
  int cpx = gridDim.x >> 3;                 // grid % 8 == 0 (mt*8)
  int swz = (bid & 7) * cpx + (bid >> 3);   // XCD-bijective; n-inner => A reuse
  int m0 = (swz >> 3) * 256;
  int n0 = (swz & 7) * 128;
  int tid = threadIdx.x;
  int wv = tid >> 6, l = tid & 63;
  int wr = wv >> 1, wc = wv & 1;            // 4M x 2N waves, 64x64 tiles

  float thr = scal[1], osc = scal[2];

  // staging addressing: thread covers row (tid>>3), XOR-preswizzled 16B chunk
  int rowq = tid >> 3;
  int swk = ((tid & 7) ^ (rowq & 7)) << 3;
  const unsigned short* gA = A + (size_t)(m0 + rowq) * KTOT + swk;
  const unsigned short* gB = W + (size_t)(n0 + rowq) * KTOT + swk;
  unsigned short* ldA = lds + wv * 512;
  unsigned short* ldB = lds + 32768 + wv * 512;

  // frag reads (XOR on read side matches staging pre-swizzle)
  int lr = l & 15;
  int kx0 = (((l >> 4) << 4) ^ ((l & 7) << 4));
  int kx1 = kx0 ^ 64;
  const char* pA = (const char*)lds + (wr * 64 + lr) * 128;
  const char* pB = (const char*)lds + 65536 + (wc * 64 + lr) * 128;

  bf16x8 af[4], bf[2];
  f32x4 acc[4][4] = {};

  // prologue: A(t0),B(t0),A(t1) = 10 loads; VM(4) -> t0 landed, A(t1) in flight
  STAGE_A(0, 0, 0);
  STAGE_A(0, 1, 0);
  STAGE_B(0, 0);
  STAGE_A(1, 0, 1);
  STAGE_A(1, 1, 1);
  VM(4);
  SBAR;

  // kan segment: tiles 0..111
  for (int t = 0; t < 112; t += 2) {
    TILE(t,     0, 1, 1, VM(4));
    TILE(t + 1, 1, 1, 1, VM(4));
  }

  // soft-threshold in-register at the kan/base boundary
#pragma unroll
  for (int i = 0; i < 4; ++i)
#pragma unroll
    for (int j = 0; j < 4; ++j)
#pragma unroll
      for (int e = 0; e < 4; ++e) {
        float v = acc[i][j][e];
        float a = fabsf(v) - thr;
        a = a > 0.f ? a : 0.f;
        acc[i][j][e] = v > 0.f ? a : -a;
      }

  // base segment: tiles 112..127
  for (int t = 112; t < 126; t += 2) {
    TILE(t,     0, 1, 1, VM(4));
    TILE(t + 1, 1, 1, 1, VM(4));
  }
  TILE(126, 0, 1, 0, VM(0));
  TILE(127, 1, 0, 0, (void)0);

  // epilogue: out = (acc + bias) * oscale
  int rr = m0 + wr * 64 + ((l >> 4) << 2);
  int cc = n0 + wc * 64 + lr;
#pragma unroll
  for (int i = 0; i < 4; ++i)
#pragma unroll
    for (int j = 0; j < 4; ++j) {
      int c = cc + j * 16;
      float bc = bias[c];
#pragma unroll
      for (int e = 0; e < 4; ++e) {
        int r = rr + i * 16 + e;
        out[(size_t)r * OUTF + c] = (acc[i][j][e] + bc) * osc;
      }
    }
}

// ---------------------------------------------------------------------------
extern "C" void kernel_launch(void* const* d_in, const int* in_sizes, int n_in,
                              void* d_out, int out_size, void* d_ws, size_t ws_size,
                              hipStream_t stream) {
  const float* x              = (const float*)d_in[0];
  const float* base_w         = (const float*)d_in[1];
  const float* base_b         = (const float*)d_in[2];
  const float* u              = (const float*)d_in[3];
  const float* translation    = (const float*)d_in[4];
  const float* scale          = (const float*)d_in[5];
  const float* wavelet_w      = (const float*)d_in[6];
  const float* soft_threshold = (const float*)d_in[7];
  const float* output_scale   = (const float*)d_in[8];
  float* out = (float*)d_out;

  char* ws = (char*)d_ws;
  float* t_vec = (float*)ws;
  float* s_vec = t_vec + 1024;
  float* scal  = s_vec + 1024;
  unsigned short* Wp = (unsigned short*)(ws + 16384);    // 16 MB
  char* dynbuf = ws + 16384 + (size_t)KTOT * OUTF * 2;

  size_t fixed = 16384 + (size_t)KTOT * OUTF * 2;
  size_t avail = ws_size > fixed ? ws_size - fixed : 0;

  mv_wt_u<<<1024, 256, 0, stream>>>(base_w, u, t_vec);
  mv_w_t<<<1024, 256, 0, stream>>>(base_w, t_vec, s_vec);
  sigma_finish<<<1, 256, 0, stream>>>(t_vec, s_vec, soft_threshold, output_scale, scal);
  wsn_cast<<<512, 256, 0, stream>>>(base_w, scal, Wp);
  wkan_cast<<<1024, 256, 0, stream>>>(wavelet_w, Wp);

  const size_t ROW = (size_t)KTOT * 2;      // A' bytes per row
  size_t total = (size_t)NROWS * ROW;
  int nch = (int)((total + (avail > 0 ? avail : 1) - 1) / (avail > 0 ? avail : 1));
  if (nch < 1) nch = 1;
  long mc = (((NROWS + nch - 1) / nch) + 255) & ~255L;
  while (mc > 256 && (size_t)mc * ROW > avail) mc -= 256;
  if (mc < 256) mc = 256;   // assume ws >= ~21 MB

  unsigned short* Ap = (unsigned short*)dynbuf;

  for (long r0 = 0; r0 < NROWS; r0 += mc) {
    long nr = (NROWS - r0 < mc) ? (NROWS - r0) : mc;
    expand_kernel<<<2048, 256, 0, stream>>>(x, translation, scale, Ap, (int)r0, (int)nr);
    int mt = (int)(nr / 256);
    gemm_k<<<mt * 8, 512, 0, stream>>>(Ap, Wp, base_b, scal, out + (size_t)r0 * OUTF);
  }
}

// Round 6
// 333.586 us; speedup vs baseline: 2.0395x; 1.0886x over previous
//
#include <hip/hip_runtime.h>
#include <math.h>

// ---------------------------------------------------------------------------
// out = (silu(x) @ (W/sigma)^T + b  +  softthr(basis(x) @ Ww^T)) * oscale
// Merged K = [kan 7168 | base 1024] = 8192, bf16 MFMA.
// BM=256 x BN=128, BK=64, 8 waves (4M x 2N, 64x64 wave tiles).
// FAT-PHASE schedule: 3 LDS buffers, stage t+2, ONE barrier per K-tile,
// counted lgkmcnt(8)/vmcnt(6), 16 MFMA per phase. softthr in-reg at tile 112.
// ---------------------------------------------------------------------------

typedef __attribute__((ext_vector_type(4))) float  f32x4;
typedef __attribute__((ext_vector_type(8))) __bf16 bf16x8;
typedef __attribute__((ext_vector_type(8))) unsigned short u16x8;

#define NROWS 16384
#define INF   1024
#define OUTF  1024
#define GG    7
#define KKAN  7168
#define KTOT  8192

static __device__ __forceinline__ unsigned short f2bf(float f) {
  union { float f; unsigned int u; } v; v.f = f;
  unsigned int r = v.u + 0x7fffu + ((v.u >> 16) & 1u);  // RNE
  return (unsigned short)(r >> 16);
}

// ---------------- sigma (spectral norm) ----------------
__global__ void mv_wt_u(const float* __restrict__ W, const float* __restrict__ u,
                        float* __restrict__ t) {
  int j = blockIdx.x;
  int tid = threadIdx.x;
  float p = 0.f;
  for (int i = tid; i < OUTF; i += 256) p += W[(size_t)i * INF + j] * u[i];
  __shared__ float red[256];
  red[tid] = p; __syncthreads();
  for (int s = 128; s > 0; s >>= 1) { if (tid < s) red[tid] += red[tid + s]; __syncthreads(); }
  if (tid == 0) t[j] = red[0];
}

__global__ void mv_w_t(const float* __restrict__ W, const float* __restrict__ t,
                       float* __restrict__ s) {
  int i = blockIdx.x;
  int tid = threadIdx.x;
  float p = 0.f;
  for (int j = tid; j < INF; j += 256) p += W[(size_t)i * INF + j] * t[j];
  __shared__ float red[256];
  red[tid] = p; __syncthreads();
  for (int k = 128; k > 0; k >>= 1) { if (tid < k) red[tid] += red[tid + k]; __syncthreads(); }
  if (tid == 0) s[i] = red[0];
}

__global__ void sigma_finish(const float* __restrict__ t, const float* __restrict__ s,
                             const float* __restrict__ st, const float* __restrict__ os,
                             float* __restrict__ scal) {
  __shared__ float r1[256], r2[256];
  int tid = threadIdx.x;
  float p1 = 0.f, p2 = 0.f;
  for (int i = tid; i < 1024; i += 256) { float a = t[i]; p1 += a * a; float b = s[i]; p2 += b * b; }
  r1[tid] = p1; r2[tid] = p2; __syncthreads();
  for (int k = 128; k > 0; k >>= 1) { if (tid < k) { r1[tid] += r1[tid + k]; r2[tid] += r2[tid + k]; } __syncthreads(); }
  if (tid == 0) {
    float nt = sqrtf(r1[0]);
    float ns = sqrtf(r2[0]);
    float nq = ns / (nt + 1e-12f);
    float sigma = nq * nq / (nq + 1e-12f);
    scal[0] = 1.f / sigma;
    scal[1] = log1pf(__expf(st[0]));
    scal[2] = os[0];
  }
}

// ---------------- weight casts into W' [1024][8192] ----------------
__global__ void wsn_cast(const float* __restrict__ w, const float* __restrict__ scal,
                         unsigned short* __restrict__ Wp) {
  float is = scal[0];
  int idx = blockIdx.x * 256 + threadIdx.x;
  int row = idx >> 7, i0 = (idx & 127) << 3;
  const f32x4* p = (const f32x4*)(w + (size_t)row * INF + i0);
  f32x4 a = p[0], b = p[1];
  u16x8 v;
  v[0] = f2bf(a[0] * is); v[1] = f2bf(a[1] * is); v[2] = f2bf(a[2] * is); v[3] = f2bf(a[3] * is);
  v[4] = f2bf(b[0] * is); v[5] = f2bf(b[1] * is); v[6] = f2bf(b[2] * is); v[7] = f2bf(b[3] * is);
  *(u16x8*)(Wp + (size_t)row * KTOT + KKAN + i0) = v;
}

__global__ void wkan_cast(const float* __restrict__ w, unsigned short* __restrict__ Wp) {
  __shared__ float row[KKAN];
  int orow = blockIdx.x;
  const float* src = w + (size_t)orow * KKAN;
  for (int c = threadIdx.x * 4; c < KKAN; c += 1024)
    *(f32x4*)&row[c] = *(const f32x4*)&src[c];
  __syncthreads();
  unsigned short* dst = Wp + (size_t)orow * KTOT;
  for (int r = threadIdx.x; r < 896; r += 256) {
    int g = r >> 7, i0 = (r & 127) << 3;
    u16x8 v;
#pragma unroll
    for (int j = 0; j < 8; j++) v[j] = f2bf(row[(i0 + j) * GG + g]);
    *(u16x8*)(dst + g * 1024 + i0) = v;
  }
}

// ---------------- activation expansion into A' [rows][8192] ----------------
__global__ void expand_kernel(const float* __restrict__ x,
                              const float* __restrict__ translation,
                              const float* __restrict__ scale,
                              unsigned short* __restrict__ Ap,
                              int row0, int nrows) {
  float tr[GG], iss[GG];
#pragma unroll
  for (int g = 0; g < GG; g++) {
    tr[g] = translation[g];
    float s = fabsf(scale[g]);
    iss[g] = 1.f / (s < 0.1f ? 0.1f : s);
  }
  int units = nrows * (INF / 8);
  int stride = gridDim.x * blockDim.x;
  for (int uu = blockIdx.x * blockDim.x + threadIdx.x; uu < units; uu += stride) {
    int nloc = uu >> 7;
    int i0 = (uu & 127) << 3;
    const f32x4* xp = (const f32x4*)(x + (size_t)(row0 + nloc) * INF + i0);
    f32x4 xa = xp[0], xb = xp[1];
    float xv[8] = {xa[0], xa[1], xa[2], xa[3], xb[0], xb[1], xb[2], xb[3]};
    u16x8 sb, kb[GG];
#pragma unroll
    for (int j = 0; j < 8; j++) {
      float xx = xv[j];
      float si = xx / (1.f + __expf(-xx));
      sb[j] = f2bf(si);
      float e2 = __expf(2.f * xx);
      float xn = 2.5f * (1.f - 2.f / (e2 + 1.f));
#pragma unroll
      for (int g = 0; g < GG; g++) {
        float xe = (xn - tr[g]) * iss[g];
        float t2 = xe * xe;
        float b = (1.f - t2) * __expf(-0.5f * t2);
        kb[g][j] = f2bf(b);
      }
    }
    unsigned short* rp = Ap + (size_t)nloc * KTOT;
    *(u16x8*)(rp + KKAN + i0) = sb;
#pragma unroll
    for (int g = 0; g < GG; g++) *(u16x8*)(rp + g * 1024 + i0) = kb[g];
  }
}

// ---------------- GEMM machinery ----------------
static __device__ __forceinline__ void gload16(const unsigned short* g, unsigned short* l) {
  __builtin_amdgcn_global_load_lds(
      (const __attribute__((address_space(1))) unsigned int*)g,
      (__attribute__((address_space(3))) unsigned int*)l, 16, 0, 0);
}

#define SCB   __builtin_amdgcn_sched_barrier(0)
#define SBAR  do { SCB; __builtin_amdgcn_s_barrier(); } while (0)
#define VM(N) asm volatile("s_waitcnt vmcnt(" #N ")" ::: "memory")
#define LG(N) asm volatile("s_waitcnt lgkmcnt(" #N ")" ::: "memory")

// stage full K-tile tt into buffer db: A 256x64 (4 gloads) + B 128x64 (2)
#define STAGE(db, tt) do { \
    const unsigned short* _sa = gA + (size_t)(tt) * 64; \
    const unsigned short* _sb = gB + (size_t)(tt) * 64; \
    unsigned short* _da = ldsS + (db) * 24576; \
    unsigned short* _db = ldsS + (db) * 24576 + 16384; \
    gload16(_sa,                       _da); \
    gload16(_sa + (size_t)64  * KTOT,  _da + 4096); \
    gload16(_sa + (size_t)128 * KTOT,  _da + 8192); \
    gload16(_sa + (size_t)192 * KTOT,  _da + 12288); \
    gload16(_sb,                       _db); \
    gload16(_sb + (size_t)64  * KTOT,  _db + 4096); \
  } while (0)

#define RD_A(dst, bb, kx) do { _Pragma("unroll") for (int i = 0; i < 4; ++i) \
    dst[i] = *(const bf16x8*)(pA + (bb) * 49152 + i * 2048 + (kx)); } while (0)

#define RD_B(dst, bb, kx) do { _Pragma("unroll") for (int j = 0; j < 4; ++j) \
    dst[j] = *(const bf16x8*)(pB + (bb) * 49152 + j * 2048 + (kx)); } while (0)

#define MM16(AF, BF) do { _Pragma("unroll") for (int i = 0; i < 4; ++i) \
    _Pragma("unroll") for (int j = 0; j < 4; ++j) \
      acc[i][j] = __builtin_amdgcn_mfma_f32_16x16x32_bf16(AF[i], BF[j], acc[i][j], 0, 0, 0); } while (0)

// one K-tile: all 16 reads + stage(t+2) + 2 fat MFMA groups + 1 barrier
#define TILE(tt, bb, db, SS, WAIT) do { \
    RD_A(af0, bb, kx0); RD_B(bf0r, bb, kx0); \
    SCB; \
    RD_A(af1, bb, kx1); RD_B(bf1r, bb, kx1); \
    SCB; \
    if (SS) STAGE(db, (tt) + 2); \
    SCB; \
    LG(8); SCB; \
    __builtin_amdgcn_s_setprio(1); MM16(af0, bf0r); __builtin_amdgcn_s_setprio(0); \
    LG(0); SCB; \
    __builtin_amdgcn_s_setprio(1); MM16(af1, bf1r); __builtin_amdgcn_s_setprio(0); \
    WAIT; \
    SBAR; \
  } while (0)

// BM=256 x BN=128, 8 waves (4M x 2N), K = 8192 merged, softthr at tile 112
__global__ __launch_bounds__(512, 2) void gemm_k(
    const unsigned short* __restrict__ A,   // [mt*256][8192] bf16
    const unsigned short* __restrict__ W,   // [1024][8192] bf16
    const float* __restrict__ bias,
    const float* __restrict__ scal,
    float* __restrict__ out) {              // [mt*256][1024]
  __shared__ unsigned short lds[73728];     // 3 buffers x 48 KB (A 32K | B 16K)

  int bid = blockIdx.x;
  int cpx = gridDim.x >> 3;                 // grid % 8 == 0 (mt*8)
  int swz = (bid & 7) * cpx + (bid >> 3);   // XCD-bijective; n-inner => A reuse
  int m0 = (swz >> 3) * 256;
  int n0 = (swz & 7) * 128;
  int tid = threadIdx.x;
  int wv = tid >> 6, l = tid & 63;
  int wr = wv >> 1, wc = wv & 1;            // 4M x 2N waves, 64x64 tiles

  float thr = scal[1], osc = scal[2];

  // staging: thread covers row (tid>>3) (+64/round), XOR-preswizzled 16B chunk
  int rowq = tid >> 3;
  int swk = ((tid & 7) ^ (rowq & 7)) << 3;
  const unsigned short* gA = A + (size_t)(m0 + rowq) * KTOT + swk;
  const unsigned short* gB = W + (size_t)(n0 + rowq) * KTOT + swk;
  unsigned short* ldsS = lds + wv * 512;    // wave-uniform dest base

  // frag reads (XOR on read side matches staging pre-swizzle)
  int lr = l & 15;
  int kx0 = (((l >> 4) << 4) ^ ((l & 7) << 4));
  int kx1 = kx0 ^ 64;
  const char* pA = (const char*)lds + (wr * 64 + lr) * 128;
  const char* pB = (const char*)lds + 32768 + (wc * 64 + lr) * 128;

  bf16x8 af0[4], af1[4], bf0r[4], bf1r[4];
  f32x4 acc[4][4] = {};

  // prologue: stage tiles 0,1 into buf 0,1; wait tile 0 landed (6 outstanding)
  STAGE(0, 0);
  STAGE(1, 1);
  VM(6);
  SBAR;

  // kan segment: tiles 0..111
  for (int t = 0; t < 108; t += 3) {
    TILE(t,     0, 2, 1, VM(6));
    TILE(t + 1, 1, 0, 1, VM(6));
    TILE(t + 2, 2, 1, 1, VM(6));
  }
  TILE(108, 0, 2, 1, VM(6));
  TILE(109, 1, 0, 1, VM(6));
  TILE(110, 2, 1, 1, VM(6));
  TILE(111, 0, 2, 1, VM(6));

  // soft-threshold in-register at the kan/base boundary
#pragma unroll
  for (int i = 0; i < 4; ++i)
#pragma unroll
    for (int j = 0; j < 4; ++j)
#pragma unroll
      for (int e = 0; e < 4; ++e) {
        float v = acc[i][j][e];
        float a = fabsf(v) - thr;
        a = a > 0.f ? a : 0.f;
        acc[i][j][e] = v > 0.f ? a : -a;
      }

  // base segment: tiles 112..127
  for (int t = 112; t < 124; t += 3) {
    TILE(t,     1, 0, 1, VM(6));
    TILE(t + 1, 2, 1, 1, VM(6));
    TILE(t + 2, 0, 2, 1, VM(6));
  }
  TILE(124, 1, 0, 1, VM(6));
  TILE(125, 2, 1, 1, VM(6));
  TILE(126, 0, 2, 0, VM(0));
  TILE(127, 1, 2, 0, (void)0);

  // epilogue: out = (acc + bias) * oscale
  int rr = m0 + wr * 64 + ((l >> 4) << 2);
  int cc = n0 + wc * 64 + lr;
#pragma unroll
  for (int i = 0; i < 4; ++i)
#pragma unroll
    for (int j = 0; j < 4; ++j) {
      int c = cc + j * 16;
      float bc = bias[c];
#pragma unroll
      for (int e = 0; e < 4; ++e) {
        int r = rr + i * 16 + e;
        out[(size_t)r * OUTF + c] = (acc[i][j][e] + bc) * osc;
      }
    }
}

// ---------------------------------------------------------------------------
extern "C" void kernel_launch(void* const* d_in, const int* in_sizes, int n_in,
                              void* d_out, int out_size, void* d_ws, size_t ws_size,
                              hipStream_t stream) {
  const float* x              = (const float*)d_in[0];
  const float* base_w         = (const float*)d_in[1];
  const float* base_b         = (const float*)d_in[2];
  const float* u              = (const float*)d_in[3];
  const float* translation    = (const float*)d_in[4];
  const float* scale          = (const float*)d_in[5];
  const float* wavelet_w      = (const float*)d_in[6];
  const float* soft_threshold = (const float*)d_in[7];
  const float* output_scale   = (const float*)d_in[8];
  float* out = (float*)d_out;

  char* ws = (char*)d_ws;
  float* t_vec = (float*)ws;
  float* s_vec = t_vec + 1024;
  float* scal  = s_vec + 1024;
  unsigned short* Wp = (unsigned short*)(ws + 16384);    // 16 MB
  char* dynbuf = ws + 16384 + (size_t)KTOT * OUTF * 2;

  size_t fixed = 16384 + (size_t)KTOT * OUTF * 2;
  size_t avail = ws_size > fixed ? ws_size - fixed : 0;

  mv_wt_u<<<1024, 256, 0, stream>>>(base_w, u, t_vec);
  mv_w_t<<<1024, 256, 0, stream>>>(base_w, t_vec, s_vec);
  sigma_finish<<<1, 256, 0, stream>>>(t_vec, s_vec, soft_threshold, output_scale, scal);
  wsn_cast<<<512, 256, 0, stream>>>(base_w, scal, Wp);
  wkan_cast<<<1024, 256, 0, stream>>>(wavelet_w, Wp);

  const size_t ROW = (size_t)KTOT * 2;      // A' bytes per row
  size_t total = (size_t)NROWS * ROW;
  int nch = (int)((total + (avail > 0 ? avail : 1) - 1) / (avail > 0 ? avail : 1));
  if (nch < 1) nch = 1;
  long mc = (((NROWS + nch - 1) / nch) + 255) & ~255L;
  while (mc > 256 && (size_t)mc * ROW > avail) mc -= 256;
  if (mc < 256) mc = 256;   // assume ws >= ~21 MB

  unsigned short* Ap = (unsigned short*)dynbuf;

  for (long r0 = 0; r0 < NROWS; r0 += mc) {
    long nr = (NROWS - r0 < mc) ? (NROWS - r0) : mc;
    expand_kernel<<<2048, 256, 0, stream>>>(x, translation, scale, Ap, (int)r0, (int)nr);
    int mt = (int)(nr / 256);
    gemm_k<<<mt * 8, 512, 0, stream>>>(Ap, Wp, base_b, scal, out + (size_t)r0 * OUTF);
  }
}